// Round 1
// baseline (688.722 us; speedup 1.0000x reference)
//
#include <hip/hip_runtime.h>
#include <stdint.h>

typedef unsigned long long u64;
typedef unsigned int u32;

#define BATCH   8
#define TOTAL   21824
#define NCLS    80
#define NCAND   3320
#define NWRD    52          /* ceil(3320/64) */
#define PADCAND 4096
#define NDET    100
#define IMGSZ   1024.0f
#define STHR    0.2f
#define NMST    0.6f

__device__ __forceinline__ float sigm(float x) { return 1.0f / (1.0f + expf(-x)); }

// Composite sort key: ascending-u64 order == (score descending, index ascending).
__device__ __forceinline__ u64 makeKey(float s, u32 idx) {
    u32 u = __float_as_uint(s);
    u32 m = u ^ ((u & 0x80000000u) ? 0xFFFFFFFFu : 0x80000000u); // ascending-order map
    return (((u64)(~m)) << 32) | (u64)idx;                        // ~m -> descending
}

__device__ void bitonicSort(u64* k, int n, int tid, int nt) {
    for (int size = 2; size <= n; size <<= 1) {
        for (int stride = size >> 1; stride > 0; stride >>= 1) {
            __syncthreads();
            for (int i = tid; i < n; i += nt) {
                int j = i ^ stride;
                if (j > i) {
                    bool up = ((i & size) == 0);
                    u64 a = k[i], b = k[j];
                    if (up ? (a > b) : (a < b)) { k[i] = b; k[j] = a; }
                }
            }
        }
    }
    __syncthreads();
}

// ---------------- Kernel 1: per-anchor max/argmax + masked score ----------------
__global__ void score_kernel(const float* __restrict__ logits, const float* __restrict__ ctr,
                             float* __restrict__ mscore, int* __restrict__ mlabel) {
    int a = blockIdx.x * blockDim.x + threadIdx.x;
    int b = blockIdx.y;
    if (a >= TOTAL) return;
    const float4* lg = (const float4*)(logits + ((size_t)(b * TOTAL + a)) * NCLS);
    float best = -1e30f; int bi = 0;
#pragma unroll
    for (int q = 0; q < NCLS / 4; q++) {
        float4 v = lg[q];
        if (v.x > best) { best = v.x; bi = 4 * q + 0; }
        if (v.y > best) { best = v.y; bi = 4 * q + 1; }
        if (v.z > best) { best = v.z; bi = 4 * q + 2; }
        if (v.w > best) { best = v.w; bi = 4 * q + 3; }
    }
    float c = ctr[(size_t)b * TOTAL + a];
    float sc = sqrtf(sigm(best) * sigm(c));
    mscore[(size_t)b * TOTAL + a] = (sc > STHR) ? sc : -1.0f;
    mlabel[(size_t)b * TOTAL + a] = bi;
}

// ---------------- candidate decode+write ----------------
__device__ __forceinline__ void writeCand(int b, int pos, u64 key, int lvlOff,
                                          const float* mscore, const int* mlabel,
                                          const float* anchors, const float* reg,
                                          float* cand_score, float* cand_box, int* cand_label) {
    int li = (int)(key & 0xFFFFFFFFu);
    int g = lvlOff + li;
    size_t bg = (size_t)b * TOTAL + g;
    float sc = mscore[bg];
    int lb = mlabel[bg];
    float4 a = ((const float4*)anchors)[g];
    float4 r = ((const float4*)reg)[bg];
    float cx = (a.x + a.z) * 0.5f;
    float cy = (a.y + a.w) * 0.5f;
    float x1 = fminf(fmaxf(cx - r.x, 0.0f), IMGSZ);
    float y1 = fminf(fmaxf(cy - r.y, 0.0f), IMGSZ);
    float x2 = fminf(fmaxf(cx + r.z, 0.0f), IMGSZ);
    float y2 = fminf(fmaxf(cy + r.w, 0.0f), IMGSZ);
    int cp = b * NCAND + pos;
    cand_score[cp] = sc;
    cand_label[cp] = lb;
    ((float4*)cand_box)[cp] = make_float4(x1, y1, x2, y2);
}

// ---------------- Kernel 2a: per-(batch, chunk) bitonic sort ----------------
// 6 chunk slots per batch: level0 split into 2x8192 (survivor keys), levels 1-4 direct.
__global__ void sort_chunks(const float* __restrict__ mscore, const int* __restrict__ mlabel,
                            const float* __restrict__ anchors, const float* __restrict__ reg,
                            u64* __restrict__ survKeys, float* __restrict__ cand_score,
                            float* __restrict__ cand_box, int* __restrict__ cand_label) {
    extern __shared__ u64 sk[];
    const int slot = blockIdx.x % 6;
    const int b = blockIdx.x / 6;
    const int lvlOffA[6] = { 0, 0, 16384, 20480, 21504, 21760 };
    const int locOffA[6] = { 0, 8192, 0, 0, 0, 0 };
    const int nA[6]      = { 8192, 8192, 4096, 1024, 256, 64 };
    const int kA[6]      = { 1000, 1000, 1000, 1000, 256, 64 };
    const int candA[6]   = { -1, -1, 1000, 2000, 3000, 3256 };
    const int survA[6]   = { 0, 1000, 0, 0, 0, 0 };
    const int lvlOff = lvlOffA[slot], locOff = locOffA[slot], n = nA[slot], k = kA[slot];
    const int tid = threadIdx.x, nt = blockDim.x;

    for (int i = tid; i < n; i += nt) {
        float s = mscore[(size_t)b * TOTAL + lvlOff + locOff + i];
        sk[i] = makeKey(s, (u32)(locOff + i));
    }
    bitonicSort(sk, n, tid, nt);

    if (candA[slot] >= 0) {
        for (int s = tid; s < k; s += nt)
            writeCand(b, candA[slot] + s, sk[s], lvlOff, mscore, mlabel, anchors, reg,
                      cand_score, cand_box, cand_label);
    } else {
        for (int s = tid; s < k; s += nt)
            survKeys[b * 2048 + survA[slot] + s] = sk[s];
    }
}

// ---------------- Kernel 2b: level-0 merge (2000 survivors -> top 1000) ----------------
__global__ void merge_l0(const float* __restrict__ mscore, const int* __restrict__ mlabel,
                         const float* __restrict__ anchors, const float* __restrict__ reg,
                         const u64* __restrict__ survKeys, float* __restrict__ cand_score,
                         float* __restrict__ cand_box, int* __restrict__ cand_label) {
    __shared__ u64 sk[2048];
    const int b = blockIdx.x, tid = threadIdx.x, nt = blockDim.x;
    for (int i = tid; i < 2048; i += nt)
        sk[i] = (i < 2000) ? survKeys[b * 2048 + i] : ~0ull;
    bitonicSort(sk, 2048, tid, nt);
    for (int s = tid; s < 1000; s += nt)
        writeCand(b, s, sk[s], 0, mscore, mlabel, anchors, reg, cand_score, cand_box, cand_label);
}

// ---------------- Kernel 3: per-batch global stable sort of 3320 candidates ----------------
__global__ void global_sort(const float* __restrict__ cand_score, const float* __restrict__ cand_box,
                            const int* __restrict__ cand_label, float* __restrict__ sscore,
                            float* __restrict__ sbox, int* __restrict__ slabel) {
    __shared__ u64 sk[PADCAND];
    const int b = blockIdx.x, tid = threadIdx.x, nt = blockDim.x;
    for (int i = tid; i < PADCAND; i += nt)
        sk[i] = (i < NCAND) ? makeKey(cand_score[b * NCAND + i], (u32)i) : ~0ull;
    bitonicSort(sk, PADCAND, tid, nt);
    for (int s = tid; s < NCAND; s += nt) {
        int idx = (int)(sk[s] & 0xFFFFFFFFu);
        sscore[b * NCAND + s] = cand_score[b * NCAND + idx];
        slabel[b * NCAND + s] = cand_label[b * NCAND + idx];
        ((float4*)sbox)[b * NCAND + s] = ((const float4*)cand_box)[b * NCAND + idx];
    }
}

// ---------------- Kernel 4: suppression bitmask matrix ----------------
// block = (64 rows, 4 word-groups); boxes (class-offset) staged in LDS.
__global__ void sup_kernel(const float* __restrict__ sbox, const int* __restrict__ slabel,
                           u64* __restrict__ sup) {
    __shared__ float4 bx[3328];
    const int b = blockIdx.y;
    const int tid = threadIdx.y * 64 + threadIdx.x;
    for (int i = tid; i < 3328; i += 256) {
        float4 v = make_float4(0.f, 0.f, 0.f, 0.f);
        if (i < NCAND) {
            v = ((const float4*)sbox)[b * NCAND + i];
            float off = (float)slabel[b * NCAND + i] * (IMGSZ + 1.0f);
            v.x = __fadd_rn(v.x, off); v.y = __fadd_rn(v.y, off);
            v.z = __fadd_rn(v.z, off); v.w = __fadd_rn(v.w, off);
        }
        bx[i] = v;
    }
    __syncthreads();
    const int i = blockIdx.x * 64 + threadIdx.x;
    if (i >= NCAND) return;
    float4 bi = bx[i];
    float ai = __fmul_rn(fmaxf(__fsub_rn(bi.z, bi.x), 0.f), fmaxf(__fsub_rn(bi.w, bi.y), 0.f));
    u64* row = sup + ((size_t)b * NCAND + i) * NWRD;
    for (int q = 0; q < 13; q++) {
        int w = threadIdx.y * 13 + q;
        u64 bits = 0;
        for (int t = 0; t < 64; t++) {
            int j = w * 64 + t;
            float4 bj = bx[j];
            float aj = __fmul_rn(fmaxf(__fsub_rn(bj.z, bj.x), 0.f), fmaxf(__fsub_rn(bj.w, bj.y), 0.f));
            float ltx = fmaxf(bi.x, bj.x), lty = fmaxf(bi.y, bj.y);
            float rbx = fminf(bi.z, bj.z), rby = fminf(bi.w, bj.w);
            float iw = fmaxf(__fsub_rn(rbx, ltx), 0.f), ih = fmaxf(__fsub_rn(rby, lty), 0.f);
            float inter = __fmul_rn(iw, ih);
            float uni = __fsub_rn(__fadd_rn(ai, aj), inter);
            float iou = __fdiv_rn(inter, fmaxf(uni, 1e-9f));
            if (iou > NMST && j > i) bits |= (1ull << t);
        }
        row[w] = bits;
    }
}

// ---------------- Kernel 5: sequential greedy scan + top-100 emit ----------------
__global__ void __launch_bounds__(64) scan_out(const u64* __restrict__ sup,
                                               const float* __restrict__ sscore,
                                               const float* __restrict__ sbox,
                                               const int* __restrict__ slabel,
                                               float* __restrict__ out) {
    const int b = blockIdx.x, lane = threadIdx.x;
    // init active mask from valid (score > thresh); lane w owns word w
    u64 act = 0;
    if (lane < NWRD) {
        for (int t = 0; t < 64; t++) {
            int j = lane * 64 + t;
            if (j < NCAND && sscore[b * NCAND + j] > STHR) act |= (1ull << t);
        }
    }
    const u64* rowBase = sup + (size_t)b * NCAND * NWRD;
    const bool ld = (lane < NWRD);
    const int D = 32;
    u64 cur[D], nxt[D];
#pragma unroll
    for (int d = 0; d < D; d++)
        cur[d] = (ld && d < NCAND) ? rowBase[(size_t)d * NWRD + lane] : 0;
    for (int base = 0; base < NCAND; base += D) {
        int nb = base + D;
#pragma unroll
        for (int d = 0; d < D; d++) {
            int i = nb + d;
            nxt[d] = (ld && i < NCAND) ? rowBase[(size_t)i * NWRD + lane] : 0;
        }
#pragma unroll
        for (int d = 0; d < D; d++) {
            int i = base + d;
            if (i < NCAND) {
                // activity bit for row i lives in lane (i>>6); fetch via readlane (uniform)
                u32 half = (u32)(act >> (i & 32));
                int word = (int)__builtin_amdgcn_readlane((int)half, i >> 6);
                if ((word >> (i & 31)) & 1) act &= ~cur[d];
            }
        }
#pragma unroll
        for (int d = 0; d < D; d++) cur[d] = nxt[d];
    }
    // rank surviving detections (word-major order == sorted order)
    int pc = __popcll(act);
    int incl = pc;
    for (int o = 1; o < 64; o <<= 1) {
        int t = __shfl_up(incl, o);
        if (lane >= o) incl += t;
    }
    int pre = incl - pc;
    int total = __shfl(incl, 63);
    __shared__ int sel[NDET];
    u64 aa = act; int r = pre;
    while (aa && r < NDET) {
        int t = __builtin_ctzll(aa);
        aa &= aa - 1;
        sel[r] = lane * 64 + t;
        r++;
    }
    __syncthreads();
    for (int s = lane; s < NDET; s += 64) {
        float4 bxv = make_float4(0.f, 0.f, 0.f, 0.f);
        float scv = 0.0f, lbv = -1.0f;
        if (s < total) {
            int idx = sel[s];
            bxv = ((const float4*)sbox)[b * NCAND + idx];
            scv = sscore[b * NCAND + idx];
            lbv = (float)slabel[b * NCAND + idx];
        }
        ((float4*)out)[b * NDET + s] = bxv;                                  // boxes [0,3200)
        out[BATCH * NDET * 4 + b * NDET + s] = scv;                          // scores [3200,4000)
        out[BATCH * NDET * 4 + BATCH * NDET + b * NDET + s] = lbv;           // labels [4000,4800)
    }
}

extern "C" void kernel_launch(void* const* d_in, const int* in_sizes, int n_in,
                              void* d_out, int out_size, void* d_ws, size_t ws_size,
                              hipStream_t stream) {
    (void)in_sizes; (void)n_in; (void)out_size; (void)ws_size;
    const float* logits  = (const float*)d_in[0];
    const float* reg     = (const float*)d_in[1];
    const float* ctr     = (const float*)d_in[2];
    const float* anchors = (const float*)d_in[3];
    float* out = (float*)d_out;

    char* ws = (char*)d_ws;
    size_t off = 0;
    auto alloc = [&](size_t bytes) -> void* {
        off = (off + 255) & ~(size_t)255;
        void* p = ws + off;
        off += bytes;
        return p;
    };
    float* mscore = (float*)alloc((size_t)BATCH * TOTAL * 4);
    int*   mlabel = (int*)  alloc((size_t)BATCH * TOTAL * 4);
    u64*   surv   = (u64*)  alloc((size_t)BATCH * 2048 * 8);
    float* cscore = (float*)alloc((size_t)BATCH * NCAND * 4);
    float* cbox   = (float*)alloc((size_t)BATCH * NCAND * 16);
    int*   clabel = (int*)  alloc((size_t)BATCH * NCAND * 4);
    float* ss     = (float*)alloc((size_t)BATCH * NCAND * 4);
    float* sb     = (float*)alloc((size_t)BATCH * NCAND * 16);
    int*   sl     = (int*)  alloc((size_t)BATCH * NCAND * 4);
    u64*   sup    = (u64*)  alloc((size_t)BATCH * NCAND * NWRD * 8);

    score_kernel<<<dim3((TOTAL + 255) / 256, BATCH), 256, 0, stream>>>(logits, ctr, mscore, mlabel);
    sort_chunks<<<BATCH * 6, 1024, 65536, stream>>>(mscore, mlabel, anchors, reg,
                                                    surv, cscore, cbox, clabel);
    merge_l0<<<BATCH, 1024, 0, stream>>>(mscore, mlabel, anchors, reg, surv, cscore, cbox, clabel);
    global_sort<<<BATCH, 1024, 0, stream>>>(cscore, cbox, clabel, ss, sb, sl);
    sup_kernel<<<dim3((NCAND + 63) / 64, BATCH), dim3(64, 4), 0, stream>>>(sb, sl, sup);
    scan_out<<<BATCH, 64, 0, stream>>>(sup, ss, sb, sl, out);
}

// Round 2
// 472.993 us; speedup vs baseline: 1.4561x; 1.4561x over previous
//
#include <hip/hip_runtime.h>
#include <stdint.h>

typedef unsigned long long u64;
typedef unsigned int u32;

#define BATCH   8
#define TOTAL   21824
#define NCLS    80
#define NCAND   3320
#define NWRD    52          /* ceil(3320/64) */
#define PADCAND 4096
#define NDET    100
#define IMGSZ   1024.0f
#define STHR    0.2f
#define NMST    0.6f

__device__ __forceinline__ float sigm(float x) { return 1.0f / (1.0f + expf(-x)); }

// Composite sort key: ascending-u64 order == (score descending, index ascending).
__device__ __forceinline__ u64 makeKey(float s, u32 idx) {
    u32 u = __float_as_uint(s);
    u32 m = u ^ ((u & 0x80000000u) ? 0xFFFFFFFFu : 0x80000000u); // ascending-order map
    return (((u64)(~m)) << 32) | (u64)idx;                        // ~m -> descending
}

__device__ void bitonicSort(u64* k, int n, int tid, int nt) {
    for (int size = 2; size <= n; size <<= 1) {
        for (int stride = size >> 1; stride > 0; stride >>= 1) {
            __syncthreads();
            for (int i = tid; i < n; i += nt) {
                int j = i ^ stride;
                if (j > i) {
                    bool up = ((i & size) == 0);
                    u64 a = k[i], b = k[j];
                    if (up ? (a > b) : (a < b)) { k[i] = b; k[j] = a; }
                }
            }
        }
    }
    __syncthreads();
}

// ---------------- Kernel 1: per-anchor max/argmax + masked score ----------------
__global__ void score_kernel(const float* __restrict__ logits, const float* __restrict__ ctr,
                             float* __restrict__ mscore, int* __restrict__ mlabel) {
    int a = blockIdx.x * blockDim.x + threadIdx.x;
    int b = blockIdx.y;
    if (a >= TOTAL) return;
    const float4* lg = (const float4*)(logits + ((size_t)(b * TOTAL + a)) * NCLS);
    float best = -1e30f; int bi = 0;
#pragma unroll
    for (int q = 0; q < NCLS / 4; q++) {
        float4 v = lg[q];
        if (v.x > best) { best = v.x; bi = 4 * q + 0; }
        if (v.y > best) { best = v.y; bi = 4 * q + 1; }
        if (v.z > best) { best = v.z; bi = 4 * q + 2; }
        if (v.w > best) { best = v.w; bi = 4 * q + 3; }
    }
    float c = ctr[(size_t)b * TOTAL + a];
    float sc = sqrtf(sigm(best) * sigm(c));
    mscore[(size_t)b * TOTAL + a] = (sc > STHR) ? sc : -1.0f;
    mlabel[(size_t)b * TOTAL + a] = bi;
}

// ---------------- candidate decode+write ----------------
__device__ __forceinline__ void writeCand(int b, int pos, u64 key, int lvlOff,
                                          const float* mscore, const int* mlabel,
                                          const float* anchors, const float* reg,
                                          float* cand_score, float* cand_box, int* cand_label) {
    int li = (int)(key & 0xFFFFFFFFu);
    int g = lvlOff + li;
    size_t bg = (size_t)b * TOTAL + g;
    float sc = mscore[bg];
    int lb = mlabel[bg];
    float4 a = ((const float4*)anchors)[g];
    float4 r = ((const float4*)reg)[bg];
    float cx = (a.x + a.z) * 0.5f;
    float cy = (a.y + a.w) * 0.5f;
    float x1 = fminf(fmaxf(cx - r.x, 0.0f), IMGSZ);
    float y1 = fminf(fmaxf(cy - r.y, 0.0f), IMGSZ);
    float x2 = fminf(fmaxf(cx + r.z, 0.0f), IMGSZ);
    float y2 = fminf(fmaxf(cy + r.w, 0.0f), IMGSZ);
    int cp = b * NCAND + pos;
    cand_score[cp] = sc;
    cand_label[cp] = lb;
    ((float4*)cand_box)[cp] = make_float4(x1, y1, x2, y2);
}

// ---------------- Kernel 2a: per-(batch, chunk) bitonic sort ----------------
__global__ void sort_chunks(const float* __restrict__ mscore, const int* __restrict__ mlabel,
                            const float* __restrict__ anchors, const float* __restrict__ reg,
                            u64* __restrict__ survKeys, float* __restrict__ cand_score,
                            float* __restrict__ cand_box, int* __restrict__ cand_label) {
    extern __shared__ u64 sk[];
    const int slot = blockIdx.x % 6;
    const int b = blockIdx.x / 6;
    const int lvlOffA[6] = { 0, 0, 16384, 20480, 21504, 21760 };
    const int locOffA[6] = { 0, 8192, 0, 0, 0, 0 };
    const int nA[6]      = { 8192, 8192, 4096, 1024, 256, 64 };
    const int kA[6]      = { 1000, 1000, 1000, 1000, 256, 64 };
    const int candA[6]   = { -1, -1, 1000, 2000, 3000, 3256 };
    const int survA[6]   = { 0, 1000, 0, 0, 0, 0 };
    const int lvlOff = lvlOffA[slot], locOff = locOffA[slot], n = nA[slot], k = kA[slot];
    const int tid = threadIdx.x, nt = blockDim.x;

    for (int i = tid; i < n; i += nt) {
        float s = mscore[(size_t)b * TOTAL + lvlOff + locOff + i];
        sk[i] = makeKey(s, (u32)(locOff + i));
    }
    bitonicSort(sk, n, tid, nt);

    if (candA[slot] >= 0) {
        for (int s = tid; s < k; s += nt)
            writeCand(b, candA[slot] + s, sk[s], lvlOff, mscore, mlabel, anchors, reg,
                      cand_score, cand_box, cand_label);
    } else {
        for (int s = tid; s < k; s += nt)
            survKeys[b * 2048 + survA[slot] + s] = sk[s];
    }
}

// ---------------- Kernel 2b: level-0 merge (2000 survivors -> top 1000) ----------------
__global__ void merge_l0(const float* __restrict__ mscore, const int* __restrict__ mlabel,
                         const float* __restrict__ anchors, const float* __restrict__ reg,
                         const u64* __restrict__ survKeys, float* __restrict__ cand_score,
                         float* __restrict__ cand_box, int* __restrict__ cand_label) {
    __shared__ u64 sk[2048];
    const int b = blockIdx.x, tid = threadIdx.x, nt = blockDim.x;
    for (int i = tid; i < 2048; i += nt)
        sk[i] = (i < 2000) ? survKeys[b * 2048 + i] : ~0ull;
    bitonicSort(sk, 2048, tid, nt);
    for (int s = tid; s < 1000; s += nt)
        writeCand(b, s, sk[s], 0, mscore, mlabel, anchors, reg, cand_score, cand_box, cand_label);
}

// ---------------- Kernel 3: per-batch global stable sort of 3320 candidates ----------------
__global__ void global_sort(const float* __restrict__ cand_score, const float* __restrict__ cand_box,
                            const int* __restrict__ cand_label, float* __restrict__ sscore,
                            float* __restrict__ sbox, int* __restrict__ slabel) {
    __shared__ u64 sk[PADCAND];
    const int b = blockIdx.x, tid = threadIdx.x, nt = blockDim.x;
    for (int i = tid; i < PADCAND; i += nt)
        sk[i] = (i < NCAND) ? makeKey(cand_score[b * NCAND + i], (u32)i) : ~0ull;
    bitonicSort(sk, PADCAND, tid, nt);
    for (int s = tid; s < NCAND; s += nt) {
        int idx = (int)(sk[s] & 0xFFFFFFFFu);
        sscore[b * NCAND + s] = cand_score[b * NCAND + idx];
        slabel[b * NCAND + s] = cand_label[b * NCAND + idx];
        ((float4*)sbox)[b * NCAND + s] = ((const float4*)cand_box)[b * NCAND + idx];
    }
}

// ---------------- Kernel 4 (fused NMS + output): greedy with find-next-active ----------------
// Key insight: scores are sorted descending, so the final top-100 = the first 100
// accepted rows of greedy NMS. Each loop iteration accepts exactly one row
// (find-next skips inactive rows), so <= 101 iterations total. Suppression for the
// accepted row is computed on the fly (boxes in LDS) — no NxN matrix needed.
__global__ void __launch_bounds__(512) nms_out(const float* __restrict__ sscore,
                                               const float* __restrict__ sbox,
                                               const int* __restrict__ slabel,
                                               float* __restrict__ out) {
    __shared__ float4 bx[NCAND];
    __shared__ u64 act[NWRD];
    __shared__ int sel[NDET];
    __shared__ int s_next;
    const int b = blockIdx.x, tid = threadIdx.x;
    const int wave = tid >> 6, lane = tid & 63;

    // Stage class-offset boxes into LDS (same bit-exact math as before).
    for (int i = tid; i < NCAND; i += 512) {
        float4 v = ((const float4*)sbox)[b * NCAND + i];
        float off = (float)slabel[b * NCAND + i] * (IMGSZ + 1.0f);
        v.x = __fadd_rn(v.x, off); v.y = __fadd_rn(v.y, off);
        v.z = __fadd_rn(v.z, off); v.w = __fadd_rn(v.w, off);
        bx[i] = v;
    }
    // Initial active mask = score > thresh. Word w via wave ballot.
#pragma unroll
    for (int k = 0; k < 7; k++) {
        int w = wave + 8 * k;
        if (w < NWRD) {
            int j = w * 64 + lane;
            bool v = (j < NCAND) && (sscore[b * NCAND + j] > STHR);
            u64 m = __ballot(v);
            if (lane == 0) act[w] = m;
        }
    }
    __syncthreads();

    int prev = -1, count = 0;
    while (true) {
        // find next active index > prev (wave 0, ballot over words)
        if (wave == 0) {
            int w0 = (prev + 1) >> 6;
            u64 m = 0;
            if (lane >= w0 && lane < NWRD) {
                m = act[lane];
                if (lane == w0) m &= (~0ull) << ((prev + 1) & 63);
            }
            u64 has = __ballot(m != 0);
            int nx = -1;
            if (has) {
                int w = __builtin_ctzll(has);
                u64 mw = __shfl(m, w);
                nx = w * 64 + __builtin_ctzll(mw);
            }
            if (lane == 0) s_next = nx;
        }
        __syncthreads();
        int i = s_next;
        if (i < 0) break;
        if (tid == 0) sel[count] = i;
        count++;
        prev = i;
        if (count >= NDET) break;

        // suppress everything row i overlaps (bit-exact IoU, no FMA contraction)
        float4 bi = bx[i];
        float ai = __fmul_rn(fmaxf(__fsub_rn(bi.z, bi.x), 0.f), fmaxf(__fsub_rn(bi.w, bi.y), 0.f));
#pragma unroll
        for (int k = 0; k < 7; k++) {
            int w = wave + 8 * k;
            if (w < NWRD) {
                int j = w * 64 + lane;
                bool s = false;
                if (j > i && j < NCAND) {
                    float4 bj = bx[j];
                    float aj = __fmul_rn(fmaxf(__fsub_rn(bj.z, bj.x), 0.f), fmaxf(__fsub_rn(bj.w, bj.y), 0.f));
                    float ltx = fmaxf(bi.x, bj.x), lty = fmaxf(bi.y, bj.y);
                    float rbx = fminf(bi.z, bj.z), rby = fminf(bi.w, bj.w);
                    float iw = fmaxf(__fsub_rn(rbx, ltx), 0.f), ih = fmaxf(__fsub_rn(rby, lty), 0.f);
                    float inter = __fmul_rn(iw, ih);
                    float uni = __fsub_rn(__fadd_rn(ai, aj), inter);
                    float iou = __fdiv_rn(inter, fmaxf(uni, 1e-9f));
                    s = (iou > NMST);
                }
                u64 bits = __ballot(s);
                if (lane == 0 && bits) act[w] &= ~bits;
            }
        }
        __syncthreads();
    }
    __syncthreads();

    // emit top-100
    for (int s = tid; s < NDET; s += 512) {
        float4 bxv = make_float4(0.f, 0.f, 0.f, 0.f);
        float scv = 0.0f, lbv = -1.0f;
        if (s < count) {
            int idx = sel[s];
            bxv = ((const float4*)sbox)[b * NCAND + idx];
            scv = sscore[b * NCAND + idx];
            lbv = (float)slabel[b * NCAND + idx];
        }
        ((float4*)out)[b * NDET + s] = bxv;                                  // boxes [0,3200)
        out[BATCH * NDET * 4 + b * NDET + s] = scv;                          // scores [3200,4000)
        out[BATCH * NDET * 4 + BATCH * NDET + b * NDET + s] = lbv;           // labels [4000,4800)
    }
}

extern "C" void kernel_launch(void* const* d_in, const int* in_sizes, int n_in,
                              void* d_out, int out_size, void* d_ws, size_t ws_size,
                              hipStream_t stream) {
    (void)in_sizes; (void)n_in; (void)out_size; (void)ws_size;
    const float* logits  = (const float*)d_in[0];
    const float* reg     = (const float*)d_in[1];
    const float* ctr     = (const float*)d_in[2];
    const float* anchors = (const float*)d_in[3];
    float* out = (float*)d_out;

    char* ws = (char*)d_ws;
    size_t off = 0;
    auto alloc = [&](size_t bytes) -> void* {
        off = (off + 255) & ~(size_t)255;
        void* p = ws + off;
        off += bytes;
        return p;
    };
    float* mscore = (float*)alloc((size_t)BATCH * TOTAL * 4);
    int*   mlabel = (int*)  alloc((size_t)BATCH * TOTAL * 4);
    u64*   surv   = (u64*)  alloc((size_t)BATCH * 2048 * 8);
    float* cscore = (float*)alloc((size_t)BATCH * NCAND * 4);
    float* cbox   = (float*)alloc((size_t)BATCH * NCAND * 16);
    int*   clabel = (int*)  alloc((size_t)BATCH * NCAND * 4);
    float* ss     = (float*)alloc((size_t)BATCH * NCAND * 4);
    float* sb     = (float*)alloc((size_t)BATCH * NCAND * 16);
    int*   sl     = (int*)  alloc((size_t)BATCH * NCAND * 4);

    score_kernel<<<dim3((TOTAL + 255) / 256, BATCH), 256, 0, stream>>>(logits, ctr, mscore, mlabel);
    sort_chunks<<<BATCH * 6, 1024, 65536, stream>>>(mscore, mlabel, anchors, reg,
                                                    surv, cscore, cbox, clabel);
    merge_l0<<<BATCH, 1024, 0, stream>>>(mscore, mlabel, anchors, reg, surv, cscore, cbox, clabel);
    global_sort<<<BATCH, 1024, 0, stream>>>(cscore, cbox, clabel, ss, sb, sl);
    nms_out<<<BATCH, 512, 0, stream>>>(ss, sb, sl, out);
}

// Round 3
// 395.716 us; speedup vs baseline: 1.7404x; 1.1953x over previous
//
#include <hip/hip_runtime.h>
#include <stdint.h>

typedef unsigned long long u64;
typedef unsigned int u32;

#define BATCH   8
#define TOTAL   21824
#define NCLS    80
#define NCAND   3320
#define NWRD    52          /* ceil(3320/64) */
#define PADCAND 4096
#define NDET    100
#define IMGSZ   1024.0f
#define STHR    0.2f
#define NMST    0.6f

__device__ __forceinline__ float sigm(float x) { return 1.0f / (1.0f + expf(-x)); }

// Order-preserving map: ascending km  ==  descending score.
__device__ __forceinline__ u32 mapKm(float s) {
    u32 u = __float_as_uint(s);
    u32 m = u ^ ((u & 0x80000000u) ? 0xFFFFFFFFu : 0x80000000u);
    return ~m;
}
// Composite sort key: ascending-u64 order == (score descending, index ascending).
__device__ __forceinline__ u64 makeKey(float s, u32 idx) {
    return (((u64)mapKm(s)) << 32) | (u64)idx;
}

__device__ void bitonicSort(u64* arr, int n, int tid, int nt) {
    for (int size = 2; size <= n; size <<= 1) {
        for (int stride = size >> 1; stride > 0; stride >>= 1) {
            __syncthreads();
            for (int i = tid; i < n; i += nt) {
                int j = i ^ stride;
                if (j > i) {
                    bool up = ((i & size) == 0);
                    u64 a = arr[i], b = arr[j];
                    if (up ? (a > b) : (a < b)) { arr[i] = b; arr[j] = a; }
                }
            }
        }
    }
    __syncthreads();
}

// ---------------- Kernel 1: per-anchor max/argmax + masked score ----------------
__global__ void score_kernel(const float* __restrict__ logits, const float* __restrict__ ctr,
                             float* __restrict__ mscore, int* __restrict__ mlabel) {
    int a = blockIdx.x * blockDim.x + threadIdx.x;
    int b = blockIdx.y;
    if (a >= TOTAL) return;
    const float4* lg = (const float4*)(logits + ((size_t)(b * TOTAL + a)) * NCLS);
    float best = -1e30f; int bi = 0;
#pragma unroll
    for (int q = 0; q < NCLS / 4; q++) {
        float4 v = lg[q];
        if (v.x > best) { best = v.x; bi = 4 * q + 0; }
        if (v.y > best) { best = v.y; bi = 4 * q + 1; }
        if (v.z > best) { best = v.z; bi = 4 * q + 2; }
        if (v.w > best) { best = v.w; bi = 4 * q + 3; }
    }
    float c = ctr[(size_t)b * TOTAL + a];
    float sc = sqrtf(sigm(best) * sigm(c));
    mscore[(size_t)b * TOTAL + a] = (sc > STHR) ? sc : -1.0f;
    mlabel[(size_t)b * TOTAL + a] = bi;
}

// ---------------- candidate decode+write ----------------
__device__ __forceinline__ void writeCand(int b, int pos, u64 key, int lvlOff,
                                          const float* mscore, const int* mlabel,
                                          const float* anchors, const float* reg,
                                          float* cand_score, float* cand_box, int* cand_label) {
    int li = (int)(key & 0xFFFFFFFFu);
    int g = lvlOff + li;
    size_t bg = (size_t)b * TOTAL + g;
    float sc = mscore[bg];
    int lb = mlabel[bg];
    float4 a = ((const float4*)anchors)[g];
    float4 r = ((const float4*)reg)[bg];
    float cx = (a.x + a.z) * 0.5f;
    float cy = (a.y + a.w) * 0.5f;
    float x1 = fminf(fmaxf(cx - r.x, 0.0f), IMGSZ);
    float y1 = fminf(fmaxf(cy - r.y, 0.0f), IMGSZ);
    float x2 = fminf(fmaxf(cx + r.z, 0.0f), IMGSZ);
    float y2 = fminf(fmaxf(cy + r.w, 0.0f), IMGSZ);
    int cp = b * NCAND + pos;
    cand_score[cp] = sc;
    cand_label[cp] = lb;
    ((float4*)cand_box)[cp] = make_float4(x1, y1, x2, y2);
}

// ---------------- Kernel 2: per-(batch,level) exact radix-select + small sort ----------------
// For n>2048: find exact k-th smallest km (4x8-bit MSD stages), gather km<=T
// (~k+dups elements, continuous scores => tiny boundary), bitonic-sort 2048.
// Top-k of that sort == exact stable top_k (key = (km, local_idx)).
__global__ void __launch_bounds__(1024) select_sort(
        const float* __restrict__ mscore, const int* __restrict__ mlabel,
        const float* __restrict__ anchors, const float* __restrict__ reg,
        float* __restrict__ cand_score, float* __restrict__ cand_box,
        int* __restrict__ cand_label) {
    __shared__ u64 sk[2048];
    __shared__ u32 hist[256], histS[256];
    __shared__ u32 sh_b, sh_cless;
    __shared__ int sh_cnt;

    const int lvl = blockIdx.x % 5, b = blockIdx.x / 5;
    const int lvlOffA[5] = { 0, 16384, 20480, 21504, 21760 };
    const int nA[5]      = { 16384, 4096, 1024, 256, 64 };
    const int kA[5]      = { 1000, 1000, 1000, 256, 64 };
    const int candA[5]   = { 0, 1000, 2000, 3000, 3256 };
    const int lvlOff = lvlOffA[lvl], n = nA[lvl], k = kA[lvl];
    const int tid = threadIdx.x, nt = 1024;
    const int lane = tid & 63;
    const float* ms = mscore + (size_t)b * TOTAL + lvlOff;

    int sortN, M;
    if (n > 2048) {
        u32 prefix = 0, need = (u32)k;
        for (int stage = 0; stage < 4; stage++) {
            int shift = 24 - 8 * stage;
            for (int i = tid; i < 256; i += nt) hist[i] = 0;
            __syncthreads();
            const int iters = n / nt;
            for (int it = 0; it < iters; it++) {
                int i = it * nt + tid;
                u32 km = mapKm(ms[i]);
                u32 bv = 256; // sentinel = not participating
                if (stage == 0 || (km >> (shift + 8)) == prefix) bv = (km >> shift) & 255u;
                // wave-aggregated histogram add (scores cluster -> few distinct bytes)
                u64 rem = __ballot(bv < 256);
                while (rem) {
                    int leader = __builtin_ctzll(rem);
                    u32 v = (u32)__shfl((int)bv, leader);
                    u64 eq = __ballot(bv == v);
                    rem &= ~eq;
                    if (lane == leader) atomicAdd(&hist[v], (u32)__popcll(eq));
                }
            }
            __syncthreads();
            // inclusive scan of hist into histS (Hillis-Steele, 256 entries)
            if (tid < 256) histS[tid] = hist[tid];
            __syncthreads();
            for (int off = 1; off < 256; off <<= 1) {
                u32 v = 0;
                if (tid < 256 && tid >= off) v = histS[tid - off];
                __syncthreads();
                if (tid < 256) histS[tid] += v;
                __syncthreads();
            }
            if (tid < 256) {
                u32 incl = histS[tid], cless = incl - hist[tid];
                if (cless < need && need <= incl) { sh_b = (u32)tid; sh_cless = cless; }
            }
            __syncthreads();
            prefix = (prefix << 8) | sh_b;
            need -= sh_cless;
            __syncthreads();
        }
        const u32 T = prefix; // exact k-th smallest km
        if (tid == 0) sh_cnt = 0;
        __syncthreads();
        const int iters = n / nt;
        for (int it = 0; it < iters; it++) {
            int i = it * nt + tid;
            u32 km = mapKm(ms[i]);
            bool take = (km <= T);
            u64 mask = __ballot(take);
            if (mask) {
                int leader = __builtin_ctzll(mask);
                int wbase = 0;
                if (lane == leader) wbase = atomicAdd(&sh_cnt, (int)__popcll(mask));
                wbase = __shfl(wbase, leader);
                if (take) {
                    int pos = wbase + (int)__popcll(mask & ((1ull << lane) - 1ull));
                    if (pos < 2048) sk[pos] = (((u64)km) << 32) | (u32)i;
                }
            }
        }
        __syncthreads();
        M = sh_cnt; if (M > 2048) M = 2048;
        sortN = 2048;
    } else {
        for (int i = tid; i < n; i += nt)
            sk[i] = (((u64)mapKm(ms[i])) << 32) | (u32)i;
        M = n; sortN = n;
        __syncthreads();
    }
    for (int i = tid; i < sortN; i += nt)
        if (i >= M) sk[i] = ~0ull;
    bitonicSort(sk, sortN, tid, nt);   // has leading/trailing barriers

    for (int s = tid; s < k; s += nt)
        writeCand(b, candA[lvl] + s, sk[s], lvlOff, mscore, mlabel, anchors, reg,
                  cand_score, cand_box, cand_label);
}

// ---------------- Kernel 3 (fused): global sort of 3320 + greedy NMS + emit ----------------
// LDS overlay: phase 1 keys (32KB) -> phase 2 class-offset boxes (53KB) reuse
// the same region; rank->cand-idx saved as u16 in non-overlapping tail.
__global__ void __launch_bounds__(1024) sort_nms(const float* __restrict__ cand_score,
                                                 const float* __restrict__ cand_box,
                                                 const int* __restrict__ cand_label,
                                                 float* __restrict__ out) {
    __shared__ char smem[59776];
    __shared__ u64 act[NWRD];
    __shared__ int sel[NDET];
    __shared__ int s_next;
    u64* sk = (u64*)smem;                                   // [0, 32768)
    float4* bx = (float4*)smem;                             // [0, 53120)
    unsigned short* sidx = (unsigned short*)(smem + 53120); // 6640 B
    const int b = blockIdx.x, tid = threadIdx.x, nt = 1024;
    const int wave = tid >> 6, lane = tid & 63;

    for (int i = tid; i < PADCAND; i += nt)
        sk[i] = (i < NCAND) ? makeKey(cand_score[b * NCAND + i], (u32)i) : ~0ull;
    bitonicSort(sk, PADCAND, tid, nt);

    // active mask init (valid <=> score > STHR <=> km < km(STHR)) + rank->idx map
    const u32 kmTHR = mapKm(STHR);
#pragma unroll
    for (int kk = 0; kk < 4; kk++) {
        int w = wave + 16 * kk;
        if (w < NWRD) {
            int j = w * 64 + lane;
            bool v = (j < NCAND) && ((u32)(sk[j] >> 32) < kmTHR);
            u64 m = __ballot(v);
            if (lane == 0) act[w] = m;
        }
    }
    for (int s = tid; s < NCAND; s += nt)
        sidx[s] = (unsigned short)(sk[s] & 0xFFFFu);
    __syncthreads();   // all key reads done; safe to overwrite with boxes

    for (int s = tid; s < NCAND; s += nt) {
        int ci = sidx[s];
        float4 v = ((const float4*)cand_box)[b * NCAND + ci];
        float off = (float)cand_label[b * NCAND + ci] * (IMGSZ + 1.0f);
        v.x = __fadd_rn(v.x, off); v.y = __fadd_rn(v.y, off);
        v.z = __fadd_rn(v.z, off); v.w = __fadd_rn(v.w, off);
        bx[s] = v;
    }
    __syncthreads();

    int prev = -1, count = 0;
    while (true) {
        if (wave == 0) {
            int w0 = (prev + 1) >> 6;
            u64 m = 0;
            if (lane >= w0 && lane < NWRD) {
                m = act[lane];
                if (lane == w0) m &= (~0ull) << ((prev + 1) & 63);
            }
            u64 has = __ballot(m != 0);
            int nx = -1;
            if (has) {
                int w = __builtin_ctzll(has);
                u64 mw = __shfl(m, w);
                nx = w * 64 + __builtin_ctzll(mw);
            }
            if (lane == 0) s_next = nx;
        }
        __syncthreads();
        int i = s_next;
        if (i < 0) break;
        if (tid == 0) sel[count] = i;
        count++;
        prev = i;
        if (count >= NDET) break;

        float4 bi = bx[i];
        float ai = __fmul_rn(fmaxf(__fsub_rn(bi.z, bi.x), 0.f), fmaxf(__fsub_rn(bi.w, bi.y), 0.f));
#pragma unroll
        for (int kk = 0; kk < 4; kk++) {
            int w = wave + 16 * kk;
            if (w < NWRD) {
                int j = w * 64 + lane;
                bool s = false;
                if (j > i && j < NCAND) {
                    float4 bj = bx[j];
                    float aj = __fmul_rn(fmaxf(__fsub_rn(bj.z, bj.x), 0.f), fmaxf(__fsub_rn(bj.w, bj.y), 0.f));
                    float ltx = fmaxf(bi.x, bj.x), lty = fmaxf(bi.y, bj.y);
                    float rbx = fminf(bi.z, bj.z), rby = fminf(bi.w, bj.w);
                    float iw = fmaxf(__fsub_rn(rbx, ltx), 0.f), ih = fmaxf(__fsub_rn(rby, lty), 0.f);
                    float inter = __fmul_rn(iw, ih);
                    float uni = __fsub_rn(__fadd_rn(ai, aj), inter);
                    float iou = __fdiv_rn(inter, fmaxf(uni, 1e-9f));
                    s = (iou > NMST);
                }
                u64 bits = __ballot(s);
                if (lane == 0 && bits) act[w] &= ~bits;
            }
        }
        __syncthreads();
    }
    __syncthreads();

    for (int s = tid; s < NDET; s += nt) {
        float4 bxv = make_float4(0.f, 0.f, 0.f, 0.f);
        float scv = 0.0f, lbv = -1.0f;
        if (s < count) {
            int ci = sidx[sel[s]];
            bxv = ((const float4*)cand_box)[b * NCAND + ci];
            scv = cand_score[b * NCAND + ci];
            lbv = (float)cand_label[b * NCAND + ci];
        }
        ((float4*)out)[b * NDET + s] = bxv;                                  // boxes [0,3200)
        out[BATCH * NDET * 4 + b * NDET + s] = scv;                          // scores [3200,4000)
        out[BATCH * NDET * 4 + BATCH * NDET + b * NDET + s] = lbv;           // labels [4000,4800)
    }
}

extern "C" void kernel_launch(void* const* d_in, const int* in_sizes, int n_in,
                              void* d_out, int out_size, void* d_ws, size_t ws_size,
                              hipStream_t stream) {
    (void)in_sizes; (void)n_in; (void)out_size; (void)ws_size;
    const float* logits  = (const float*)d_in[0];
    const float* reg     = (const float*)d_in[1];
    const float* ctr     = (const float*)d_in[2];
    const float* anchors = (const float*)d_in[3];
    float* out = (float*)d_out;

    char* ws = (char*)d_ws;
    size_t off = 0;
    auto alloc = [&](size_t bytes) -> void* {
        off = (off + 255) & ~(size_t)255;
        void* p = ws + off;
        off += bytes;
        return p;
    };
    float* mscore = (float*)alloc((size_t)BATCH * TOTAL * 4);
    int*   mlabel = (int*)  alloc((size_t)BATCH * TOTAL * 4);
    float* cscore = (float*)alloc((size_t)BATCH * NCAND * 4);
    float* cbox   = (float*)alloc((size_t)BATCH * NCAND * 16);
    int*   clabel = (int*)  alloc((size_t)BATCH * NCAND * 4);

    score_kernel<<<dim3((TOTAL + 255) / 256, BATCH), 256, 0, stream>>>(logits, ctr, mscore, mlabel);
    select_sort<<<BATCH * 5, 1024, 0, stream>>>(mscore, mlabel, anchors, reg,
                                                cscore, cbox, clabel);
    sort_nms<<<BATCH, 1024, 0, stream>>>(cscore, cbox, clabel, out);
}

// Round 4
// 308.578 us; speedup vs baseline: 2.2319x; 1.2824x over previous
//
#include <hip/hip_runtime.h>
#include <stdint.h>

typedef unsigned long long u64;
typedef unsigned int u32;
typedef unsigned short u16;

#define BATCH   8
#define TOTAL   21824
#define NCLS    80
#define NCAND   3320
#define NWRD    52          /* ceil(3320/64) */
#define NW32    104         /* ceil(3320/32) */
#define NDET    100
#define IMGSZ   1024.0f
#define STHR    0.2f
#define NMST    0.6f

__device__ __forceinline__ float sigm(float x) { return 1.0f / (1.0f + expf(-x)); }

// Order-preserving map: ascending km == descending score.
__device__ __forceinline__ u32 mapKm(float s) {
    u32 u = __float_as_uint(s);
    u32 m = u ^ ((u & 0x80000000u) ? 0xFFFFFFFFu : 0x80000000u);
    return ~m;
}
// Composite sort key: ascending-u64 order == (score descending, index ascending).
__device__ __forceinline__ u64 makeKey(float s, u32 idx) {
    return (((u64)mapKm(s)) << 32) | (u64)idx;
}

// Bit-exact IoU suppression test (no FMA contraction) — must stay identical
// everywhere it is used so selection matches the numpy reference.
__device__ __forceinline__ bool suppress(float4 a, float4 c) {
    float aa = __fmul_rn(fmaxf(__fsub_rn(a.z, a.x), 0.f), fmaxf(__fsub_rn(a.w, a.y), 0.f));
    float ac = __fmul_rn(fmaxf(__fsub_rn(c.z, c.x), 0.f), fmaxf(__fsub_rn(c.w, c.y), 0.f));
    float ltx = fmaxf(a.x, c.x), lty = fmaxf(a.y, c.y);
    float rbx = fminf(a.z, c.z), rby = fminf(a.w, c.w);
    float iw = fmaxf(__fsub_rn(rbx, ltx), 0.f), ih = fmaxf(__fsub_rn(rby, lty), 0.f);
    float inter = __fmul_rn(iw, ih);
    float uni = __fsub_rn(__fadd_rn(aa, ac), inter);
    float iou = __fdiv_rn(inter, fmaxf(uni, 1e-9f));
    return iou > NMST;
}

// ---------------- Kernel 1: per-anchor max/argmax + masked score ----------------
__global__ void score_kernel(const float* __restrict__ logits, const float* __restrict__ ctr,
                             float* __restrict__ mscore, int* __restrict__ mlabel) {
    int a = blockIdx.x * blockDim.x + threadIdx.x;
    int b = blockIdx.y;
    if (a >= TOTAL) return;
    const float4* lg = (const float4*)(logits + ((size_t)(b * TOTAL + a)) * NCLS);
    float best = -1e30f; int bi = 0;
#pragma unroll
    for (int q = 0; q < NCLS / 4; q++) {
        float4 v = lg[q];
        if (v.x > best) { best = v.x; bi = 4 * q + 0; }
        if (v.y > best) { best = v.y; bi = 4 * q + 1; }
        if (v.z > best) { best = v.z; bi = 4 * q + 2; }
        if (v.w > best) { best = v.w; bi = 4 * q + 3; }
    }
    float c = ctr[(size_t)b * TOTAL + a];
    float sc = sqrtf(sigm(best) * sigm(c));
    mscore[(size_t)b * TOTAL + a] = (sc > STHR) ? sc : -1.0f;
    mlabel[(size_t)b * TOTAL + a] = bi;
}

// ---------------- candidate decode+write ----------------
__device__ __forceinline__ void writeCand(int b, int pos, u64 key, int lvlOff,
                                          const float* mscore, const int* mlabel,
                                          const float* anchors, const float* reg,
                                          float* cand_score, float* cand_box, int* cand_label) {
    int li = (int)(key & 0xFFFFFFFFu);
    int g = lvlOff + li;
    size_t bg = (size_t)b * TOTAL + g;
    float sc = mscore[bg];
    int lb = mlabel[bg];
    float4 a = ((const float4*)anchors)[g];
    float4 r = ((const float4*)reg)[bg];
    float cx = (a.x + a.z) * 0.5f;
    float cy = (a.y + a.w) * 0.5f;
    float x1 = fminf(fmaxf(cx - r.x, 0.0f), IMGSZ);
    float y1 = fminf(fmaxf(cy - r.y, 0.0f), IMGSZ);
    float x2 = fminf(fmaxf(cx + r.z, 0.0f), IMGSZ);
    float y2 = fminf(fmaxf(cy + r.w, 0.0f), IMGSZ);
    int cp = b * NCAND + pos;
    cand_score[cp] = sc;
    cand_label[cp] = lb;
    ((float4*)cand_box)[cp] = make_float4(x1, y1, x2, y2);
}

// ---------------- Kernel 2: per-(batch,level) exact radix-select + rank placement ----------------
// n>2048: exact k-th smallest km via 4x8-bit MSD histogram stages, gather km<=T,
// then place by rank-by-counting (broadcast LDS reads, no barriers) — exact stable top_k.
__global__ void __launch_bounds__(1024) select_sort(
        const float* __restrict__ mscore, const int* __restrict__ mlabel,
        const float* __restrict__ anchors, const float* __restrict__ reg,
        float* __restrict__ cand_score, float* __restrict__ cand_box,
        int* __restrict__ cand_label) {
    __shared__ u64 sk[2048];
    __shared__ u32 hist[256];
    __shared__ u32 sh_b, sh_cless;
    __shared__ int sh_cnt;

    const int lvl = blockIdx.x % 5, b = blockIdx.x / 5;
    const int lvlOffA[5] = { 0, 16384, 20480, 21504, 21760 };
    const int nA[5]      = { 16384, 4096, 1024, 256, 64 };
    const int kA[5]      = { 1000, 1000, 1000, 256, 64 };
    const int candA[5]   = { 0, 1000, 2000, 3000, 3256 };
    const int lvlOff = lvlOffA[lvl], n = nA[lvl], k = kA[lvl];
    const int tid = threadIdx.x, nt = 1024;
    const int lane = tid & 63;
    const float* ms = mscore + (size_t)b * TOTAL + lvlOff;

    int m0;
    if (n > 2048) {
        u32 prefix = 0, need = (u32)k;
        for (int stage = 0; stage < 4; stage++) {
            int shift = 24 - 8 * stage;
            for (int i = tid; i < 256; i += nt) hist[i] = 0;
            __syncthreads();
            const int iters = n / nt;
            for (int it = 0; it < iters; it++) {
                int i = it * nt + tid;
                u32 km = mapKm(ms[i]);
                u32 bv = 256; // sentinel = not participating
                if (stage == 0 || (km >> (shift + 8)) == prefix) bv = (km >> shift) & 255u;
                // wave-aggregated histogram add (few distinct bytes per wave)
                u64 rem = __ballot(bv < 256);
                while (rem) {
                    int leader = __builtin_ctzll(rem);
                    u32 v = (u32)__shfl((int)bv, leader);
                    u64 eq = __ballot(bv == v);
                    rem &= ~eq;
                    if (lane == leader) atomicAdd(&hist[v], (u32)__popcll(eq));
                }
            }
            __syncthreads();
            // single-wave scan over 256 buckets: lane l owns buckets 4l..4l+3
            if (tid < 64) {
                u32 h0 = hist[4 * tid + 0], h1 = hist[4 * tid + 1];
                u32 h2 = hist[4 * tid + 2], h3 = hist[4 * tid + 3];
                int s = (int)(h0 + h1 + h2 + h3);
                int incl = s;
                for (int o = 1; o < 64; o <<= 1) {
                    int t = __shfl_up(incl, o);
                    if (tid >= o) incl += t;
                }
                u32 c = (u32)(incl - s);
                u32 hh[4] = { h0, h1, h2, h3 };
#pragma unroll
                for (int q = 0; q < 4; q++) {
                    u32 cless = c; c += hh[q];
                    if (cless < need && need <= c) { sh_b = (u32)(4 * tid + q); sh_cless = cless; }
                }
            }
            __syncthreads();
            prefix = (prefix << 8) | sh_b;
            need -= sh_cless;
            __syncthreads();
        }
        const u32 T = prefix; // exact k-th smallest km
        if (tid == 0) sh_cnt = 0;
        __syncthreads();
        const int iters = n / nt;
        for (int it = 0; it < iters; it++) {
            int i = it * nt + tid;
            u32 km = mapKm(ms[i]);
            bool take = (km <= T);
            u64 mask = __ballot(take);
            if (mask) {
                int leader = __builtin_ctzll(mask);
                int wbase = 0;
                if (lane == leader) wbase = atomicAdd(&sh_cnt, (int)__popcll(mask));
                wbase = __shfl(wbase, leader);
                if (take) {
                    int pos = wbase + (int)__popcll(mask & ((1ull << lane) - 1ull));
                    if (pos < 2048) sk[pos] = (((u64)km) << 32) | (u32)i;
                }
            }
        }
        __syncthreads();
        m0 = sh_cnt; if (m0 > 2048) m0 = 2048;
    } else {
        for (int i = tid; i < n; i += nt)
            sk[i] = (((u64)mapKm(ms[i])) << 32) | (u32)i;
        m0 = n;
        __syncthreads();
    }

    // rank-by-counting: thread owns up to 2 elements; loop over m0 keys via
    // wave-uniform (broadcast, conflict-free) LDS reads. Zero barriers.
    u64 k0 = ~0ull, k1 = ~0ull;
    bool h0 = tid < m0, h1 = tid + 1024 < m0;
    if (h0) k0 = sk[tid];
    if (h1) k1 = sk[tid + 1024];
    int r0 = 0, r1 = 0;
    for (int f = 0; f < m0; f++) {
        u64 kf = sk[f];
        r0 += (kf < k0);
        r1 += (kf < k1);
    }
    if (h0 && r0 < k)
        writeCand(b, candA[lvl] + r0, k0, lvlOff, mscore, mlabel, anchors, reg,
                  cand_score, cand_box, cand_label);
    if (h1 && r1 < k)
        writeCand(b, candA[lvl] + r1, k1, lvlOff, mscore, mlabel, anchors, reg,
                  cand_score, cand_box, cand_label);
}

// ---------------- Kernel 3 (fused): merge-by-rank + windowed greedy NMS + emit ----------------
__global__ void __launch_bounds__(1024) sort_nms(const float* __restrict__ cand_score,
                                                 const float* __restrict__ cand_box,
                                                 const int* __restrict__ cand_label,
                                                 float* __restrict__ out) {
    __shared__ __align__(16) char regA[53120];      // phase1: u64 keys[3320]; phase2: float4 bx[3320]
    __shared__ u16 sidx[NCAND];                     // rank -> cand index
    __shared__ u32 act32[NW32];
    __shared__ int sel[NDET];
    __shared__ u16 win[64];
    __shared__ float4 wb[64];
    __shared__ u64 wsup[64];
    __shared__ int s_nwin, s_count;
    __shared__ u64 s_accM;

    const int b = blockIdx.x, tid = threadIdx.x, nt = 1024;
    const int wave = tid >> 6, lane = tid & 63;
    const int segStart[5] = { 0, 1000, 2000, 3000, 3256 };
    const int segLen[5]   = { 1000, 1000, 1000, 256, 64 };

    u64* keys = (u64*)regA;
    float4* bx = (float4*)regA;

    // Phase 1a: build composite keys (each level segment is already sorted ascending).
    for (int p = tid; p < NCAND; p += nt)
        keys[p] = makeKey(cand_score[b * NCAND + p], (u32)p);
    for (int i = tid; i < NW32; i += nt) act32[i] = 0;
    __syncthreads();

    // Phase 1b: merge-by-rank — global rank = local rank + binary-search counts
    // in the 4 other sorted segments. All keys distinct (idx field).
    const u32 kmTHR = mapKm(STHR);
    for (int p = tid; p < NCAND; p += nt) {
        u64 K = keys[p];
        int lvl = (p < 1000) ? 0 : (p < 2000) ? 1 : (p < 3000) ? 2 : (p < 3256) ? 3 : 4;
        int rank = p - segStart[lvl];
#pragma unroll
        for (int s2 = 0; s2 < 5; s2++) {
            if (s2 == lvl) continue;
            int lo = 0, hi = segLen[s2], base = segStart[s2];
            while (lo < hi) {
                int mid = (lo + hi) >> 1;
                if (keys[base + mid] < K) lo = mid + 1; else hi = mid;
            }
            rank += lo;
        }
        sidx[rank] = (u16)p;
        if ((u32)(K >> 32) < kmTHR)   // score > STHR
            atomicOr(&act32[rank >> 5], 1u << (rank & 31));
    }
    __syncthreads();

    // Phase 2: stage class-offset boxes in sorted order (overwrites keys region).
    for (int q = tid; q < NCAND; q += nt) {
        int p = sidx[q];
        float4 v = ((const float4*)cand_box)[b * NCAND + p];
        float off = (float)cand_label[b * NCAND + p] * (IMGSZ + 1.0f);
        v.x = __fadd_rn(v.x, off); v.y = __fadd_rn(v.y, off);
        v.z = __fadd_rn(v.z, off); v.w = __fadd_rn(v.w, off);
        bx[q] = v;
    }
    __syncthreads();

    // Phase 3: windowed greedy NMS. Window = next 64 active rows (in order);
    // resolve greedy inside the window (reg bitmasks, wave 0), append accepted,
    // apply accepted suppression to the tail. Exactly greedy-NMS semantics.
    int count = 0;
    while (true) {
        // gather next <=64 active ranks into win[]
        if (wave == 0) {
            u64 m = 0;
            if (lane < NWRD) m = (u64)act32[2 * lane] | ((u64)act32[2 * lane + 1] << 32);
            int c = __popcll(m);
            int incl = c;
            for (int o = 1; o < 64; o <<= 1) {
                int t = __shfl_up(incl, o);
                if (lane >= o) incl += t;
            }
            int pre = incl - c;
            int total = __shfl(incl, 63);
            int take = total < 64 ? total : 64;
            if (lane == 0) s_nwin = take;
            u64 mm = m; int r = 0;
            while (mm && (pre + r) < take) {
                int t = __builtin_ctzll(mm); mm &= mm - 1;
                win[pre + r] = (u16)(lane * 64 + t);
                r++;
            }
        }
        __syncthreads();
        const int nwin = s_nwin;
        if (nwin == 0) break;

        for (int t = tid; t < nwin; t += nt) wb[t] = bx[win[t]];
        __syncthreads();

        // pairwise window suppression masks: wsup[r] bit c == (r suppresses c), c>r
#pragma unroll
        for (int kk = 0; kk < 4; kk++) {
            int r = wave + 16 * kk;
            bool sp = false;
            if (r < nwin && lane < nwin && lane > r) sp = suppress(wb[r], wb[lane]);
            u64 mask = __ballot(sp);
            if (lane == 0) wsup[r] = mask;
        }
        __syncthreads();

        // greedy resolve within window (wave 0, registers only)
        if (wave == 0) {
            u64 supr = (lane < nwin) ? wsup[lane] : 0;
            u64 aliveM = (nwin >= 64) ? ~0ull : ((1ull << nwin) - 1ull);
            u64 accM = 0;
            for (int r = 0; r < nwin; r++) {
                if ((aliveM >> r) & 1) {
                    accM |= 1ull << r;
                    u64 sr = __shfl(supr, r);
                    aliveM &= ~sr;
                }
            }
            int na = __popcll(accM);
            int space = NDET - count;
            int takeA = na < space ? na : space;
            if (lane < nwin && ((accM >> lane) & 1)) {
                int pos = __popcll(accM & ((1ull << lane) - 1ull));
                if (pos < takeA) sel[count + pos] = (int)win[lane];
            }
            if (lane == 0) { s_count = count + takeA; s_accM = accM; }
        }
        __syncthreads();
        count = s_count;
        u64 accM = s_accM;
        if (count >= NDET) break;

        // clear all window rows from the active set
        for (int t = tid; t < nwin; t += nt) {
            int q = win[t];
            atomicAnd(&act32[q >> 5], ~(1u << (q & 31)));
        }
        // apply accepted suppression to remaining active rows (all have rank > window)
        for (int j = tid; j < NCAND; j += nt) {
            if ((act32[j >> 5] >> (j & 31)) & 1) {
                float4 bj = bx[j];
                u64 am = accM;
                while (am) {
                    int r = __builtin_ctzll(am); am &= am - 1;
                    if (suppress(wb[r], bj)) {
                        atomicAnd(&act32[j >> 5], ~(1u << (j & 31)));
                        break;
                    }
                }
            }
        }
        __syncthreads();
    }
    __syncthreads();

    // emit top-100
    for (int s = tid; s < NDET; s += nt) {
        float4 bxv = make_float4(0.f, 0.f, 0.f, 0.f);
        float scv = 0.0f, lbv = -1.0f;
        if (s < count) {
            int ci = sidx[sel[s]];
            bxv = ((const float4*)cand_box)[b * NCAND + ci];
            scv = cand_score[b * NCAND + ci];
            lbv = (float)cand_label[b * NCAND + ci];
        }
        ((float4*)out)[b * NDET + s] = bxv;                                  // boxes [0,3200)
        out[BATCH * NDET * 4 + b * NDET + s] = scv;                          // scores [3200,4000)
        out[BATCH * NDET * 4 + BATCH * NDET + b * NDET + s] = lbv;           // labels [4000,4800)
    }
}

extern "C" void kernel_launch(void* const* d_in, const int* in_sizes, int n_in,
                              void* d_out, int out_size, void* d_ws, size_t ws_size,
                              hipStream_t stream) {
    (void)in_sizes; (void)n_in; (void)out_size; (void)ws_size;
    const float* logits  = (const float*)d_in[0];
    const float* reg     = (const float*)d_in[1];
    const float* ctr     = (const float*)d_in[2];
    const float* anchors = (const float*)d_in[3];
    float* out = (float*)d_out;

    char* ws = (char*)d_ws;
    size_t off = 0;
    auto alloc = [&](size_t bytes) -> void* {
        off = (off + 255) & ~(size_t)255;
        void* p = ws + off;
        off += bytes;
        return p;
    };
    float* mscore = (float*)alloc((size_t)BATCH * TOTAL * 4);
    int*   mlabel = (int*)  alloc((size_t)BATCH * TOTAL * 4);
    float* cscore = (float*)alloc((size_t)BATCH * NCAND * 4);
    float* cbox   = (float*)alloc((size_t)BATCH * NCAND * 16);
    int*   clabel = (int*)  alloc((size_t)BATCH * NCAND * 4);

    score_kernel<<<dim3((TOTAL + 255) / 256, BATCH), 256, 0, stream>>>(logits, ctr, mscore, mlabel);
    select_sort<<<BATCH * 5, 1024, 0, stream>>>(mscore, mlabel, anchors, reg,
                                                cscore, cbox, clabel);
    sort_nms<<<BATCH, 1024, 0, stream>>>(cscore, cbox, clabel, out);
}

// Round 5
// 301.751 us; speedup vs baseline: 2.2824x; 1.0226x over previous
//
#include <hip/hip_runtime.h>
#include <stdint.h>

typedef unsigned long long u64;
typedef unsigned int u32;
typedef unsigned short u16;

#define BATCH   8
#define TOTAL   21824
#define NCLS    80
#define NCAND   3320
#define NWRD    52          /* ceil(3320/64) */
#define NW32    104         /* ceil(3320/32) */
#define NDET    100
#define IMGSZ   1024.0f
#define STHR    0.2f
#define NMST    0.6f
#define NBUCK   65536       /* 16-bit buckets of km */

__device__ __forceinline__ float sigm(float x) { return 1.0f / (1.0f + expf(-x)); }

// Order-preserving map: ascending km == descending score.
__device__ __forceinline__ u32 mapKm(float s) {
    u32 u = __float_as_uint(s);
    u32 m = u ^ ((u & 0x80000000u) ? 0xFFFFFFFFu : 0x80000000u);
    return ~m;
}
// Composite sort key: ascending-u64 order == (score descending, index ascending).
__device__ __forceinline__ u64 makeKey(float s, u32 idx) {
    return (((u64)mapKm(s)) << 32) | (u64)idx;
}

// Bit-exact IoU suppression test (no FMA contraction) — must stay identical
// everywhere it is used so selection matches the numpy reference.
__device__ __forceinline__ bool suppress(float4 a, float4 c) {
    float aa = __fmul_rn(fmaxf(__fsub_rn(a.z, a.x), 0.f), fmaxf(__fsub_rn(a.w, a.y), 0.f));
    float ac = __fmul_rn(fmaxf(__fsub_rn(c.z, c.x), 0.f), fmaxf(__fsub_rn(c.w, c.y), 0.f));
    float ltx = fmaxf(a.x, c.x), lty = fmaxf(a.y, c.y);
    float rbx = fminf(a.z, c.z), rby = fminf(a.w, c.w);
    float iw = fmaxf(__fsub_rn(rbx, ltx), 0.f), ih = fmaxf(__fsub_rn(rby, lty), 0.f);
    float inter = __fmul_rn(iw, ih);
    float uni = __fsub_rn(__fadd_rn(aa, ac), inter);
    float iou = __fdiv_rn(inter, fmaxf(uni, 1e-9f));
    return iou > NMST;
}

// ---------------- Kernel 1: coalesced score/argmax + fused global histogram ----------------
// 4 lanes per anchor row: each load instruction covers 16 rows x 64B contiguous.
__global__ __launch_bounds__(256) void score_kernel(
        const float* __restrict__ logits, const float* __restrict__ ctr,
        float* __restrict__ mscore, int* __restrict__ mlabel, u32* __restrict__ hist) {
    const int b = blockIdx.y;
    const int tid = threadIdx.x;
    const int wave = tid >> 6, lane = tid & 63;
    const int g = lane >> 2, j = lane & 3;
    const int rowBase = blockIdx.x * 256 + wave * 64;
#pragma unroll
    for (int t = 0; t < 4; t++) {
        int r = rowBase + 16 * t + g;
        bool valid = r < TOTAL;
        float best = -1e30f; int bi = 0;
        if (valid) {
            const float* rowp = logits + ((size_t)b * TOTAL + r) * NCLS + j * 4;
#pragma unroll
            for (int u = 0; u < 5; u++) {
                float4 v = *(const float4*)(rowp + u * 16);
                int c0 = u * 16 + j * 4;
                if (v.x > best) { best = v.x; bi = c0; }
                if (v.y > best) { best = v.y; bi = c0 + 1; }
                if (v.z > best) { best = v.z; bi = c0 + 2; }
                if (v.w > best) { best = v.w; bi = c0 + 3; }
            }
        }
        // merge 4 lanes of one row: max, tie -> lowest class index (first occurrence)
#pragma unroll
        for (int off = 1; off <= 2; off <<= 1) {
            float ob = __shfl_xor(best, off);
            int obi = __shfl_xor(bi, off);
            if (ob > best || (ob == best && obi < bi)) { best = ob; bi = obi; }
        }
        if (valid && j == 0) {
            float c = ctr[(size_t)b * TOTAL + r];
            float sc = sqrtf(sigm(best) * sigm(c));
            float msc = (sc > STHR) ? sc : -1.0f;
            mscore[(size_t)b * TOTAL + r] = msc;
            mlabel[(size_t)b * TOTAL + r] = bi;
            int lvl = (r < 16384) ? 0 : (r < 20480) ? 1 : (r < 21504) ? 2 : (r < 21760) ? 3 : 4;
            atomicAdd(&hist[(size_t)(b * 5 + lvl) * NBUCK + (mapKm(msc) >> 16)], 1u);
        }
    }
}

// ---------------- candidate decode+write ----------------
__device__ __forceinline__ void writeCand(int b, int pos, u64 key, int lvlOff,
                                          const float* mscore, const int* mlabel,
                                          const float* anchors, const float* reg,
                                          float* cand_score, float* cand_box, int* cand_label) {
    int li = (int)(key & 0xFFFFFFFFu);
    int g = lvlOff + li;
    size_t bg = (size_t)b * TOTAL + g;
    float sc = mscore[bg];
    int lb = mlabel[bg];
    float4 a = ((const float4*)anchors)[g];
    float4 r = ((const float4*)reg)[bg];
    float cx = (a.x + a.z) * 0.5f;
    float cy = (a.y + a.w) * 0.5f;
    float x1 = fminf(fmaxf(cx - r.x, 0.0f), IMGSZ);
    float y1 = fminf(fmaxf(cy - r.y, 0.0f), IMGSZ);
    float x2 = fminf(fmaxf(cx + r.z, 0.0f), IMGSZ);
    float y2 = fminf(fmaxf(cy + r.w, 0.0f), IMGSZ);
    int cp = b * NCAND + pos;
    cand_score[cp] = sc;
    cand_label[cp] = lb;
    ((float4*)cand_box)[cp] = make_float4(x1, y1, x2, y2);
}

// ---------------- Kernel 2: per-(batch,level) exact k-th composite key from histogram ----------------
__global__ __launch_bounds__(256) void cutoff_kernel(const float* __restrict__ mscore,
                                                     const u32* __restrict__ hist,
                                                     u64* __restrict__ cutKey) {
    __shared__ u32 chunkSum[256];
    __shared__ int sh_chunk; __shared__ u32 sh_cbase;
    __shared__ u32 sh_B, sh_cless;
    __shared__ int sh_m;
    __shared__ u64 cl[2048];
    const int lvl = blockIdx.x % 5, b = blockIdx.x / 5;
    const int lvlOffA[5] = { 0, 16384, 20480, 21504, 21760 };
    const int nA[5]      = { 16384, 4096, 1024, 256, 64 };
    const int kA[5]      = { 1000, 1000, 1000, 256, 64 };
    const int n = nA[lvl]; const u32 k = (u32)kA[lvl];
    const int tid = threadIdx.x, wave = tid >> 6, lane = tid & 63;
    const u32* H = hist + (size_t)(b * 5 + lvl) * NBUCK;
    const float* ms = mscore + (size_t)b * TOTAL + lvlOffA[lvl];

    // per-chunk (256 buckets) sums, wave-parallel coalesced
    for (int c = wave; c < 256; c += 4) {
        u32 s = 0;
#pragma unroll
        for (int q = 0; q < 4; q++) s += H[c * 256 + q * 64 + lane];
        for (int o = 32; o > 0; o >>= 1) s += __shfl_down(s, o);
        if (lane == 0) chunkSum[c] = s;
    }
    __syncthreads();
    // wave 0: find chunk containing the k-th smallest
    if (wave == 0) {
        u32 h4[4]; u32 s = 0;
#pragma unroll
        for (int q = 0; q < 4; q++) { h4[q] = chunkSum[4 * lane + q]; s += h4[q]; }
        u32 incl = s;
        for (int o = 1; o < 64; o <<= 1) { u32 t2 = __shfl_up(incl, o); if (lane >= o) incl += t2; }
        u32 base = incl - s;
#pragma unroll
        for (int q = 0; q < 4; q++) {
            u32 E = base; base += h4[q];
            if (E < k && k <= base) { sh_chunk = 4 * lane + q; sh_cbase = E; }
        }
    }
    __syncthreads();
    const int cstar = sh_chunk; const u32 cbase = sh_cbase;
    // wave 0: find bucket within chunk
    if (wave == 0) {
        uint4 hv = ((const uint4*)(H + cstar * 256))[lane];
        u32 s = hv.x + hv.y + hv.z + hv.w;
        u32 incl = s;
        for (int o = 1; o < 64; o <<= 1) { u32 t2 = __shfl_up(incl, o); if (lane >= o) incl += t2; }
        u32 base = cbase + incl - s;
        u32 hh[4] = { hv.x, hv.y, hv.z, hv.w };
#pragma unroll
        for (int q = 0; q < 4; q++) {
            u32 E = base; base += hh[q];
            if (E < k && k <= base) { sh_B = (u32)(cstar * 256 + 4 * lane + q); sh_cless = E; }
        }
    }
    if (tid == 0) sh_m = 0;
    __syncthreads();
    const u32 Bstar = sh_B, cless = sh_cless;
    const u32 need = k - cless;      // >= 1 by construction
    // collect the boundary bucket's members
    for (int i = tid; i < n; i += 256) {
        u32 km = mapKm(ms[i]);
        if ((km >> 16) == Bstar) {
            int pos = atomicAdd(&sh_m, 1);
            if (pos < 2048) cl[pos] = (((u64)km) << 32) | (u32)i;
        }
    }
    __syncthreads();
    int m = sh_m; if (m > 2048) m = 2048;
    // exact rank of each member; the (need-1)-ranked key is the k-th smallest overall
    u64 own[8]; int rk[8]; int nown = 0;
    for (int p = tid; p < m; p += 256) { own[nown] = cl[p]; rk[nown] = 0; nown++; }
    for (int f = 0; f < m; f++) {
        u64 kf = cl[f];
        for (int q2 = 0; q2 < nown; q2++) rk[q2] += (kf < own[q2]);
    }
    for (int q2 = 0; q2 < nown; q2++)
        if ((u32)rk[q2] == need - 1) cutKey[b * 5 + lvl] = own[q2];
}

// ---------------- Kernel 3: gather candidates (key <= cutKey), rank, writeCand ----------------
__global__ __launch_bounds__(512) void place_kernel(
        const float* __restrict__ mscore, const int* __restrict__ mlabel,
        const float* __restrict__ anchors, const float* __restrict__ reg,
        const u64* __restrict__ cutKey, float* __restrict__ cand_score,
        float* __restrict__ cand_box, int* __restrict__ cand_label) {
    __shared__ u64 keys[1024];
    __shared__ int sh_cnt;
    const int lvl = blockIdx.x % 5, b = blockIdx.x / 5;
    const int lvlOffA[5] = { 0, 16384, 20480, 21504, 21760 };
    const int nA[5]      = { 16384, 4096, 1024, 256, 64 };
    const int candA[5]   = { 0, 1000, 2000, 3000, 3256 };
    const int n = nA[lvl], lvlOff = lvlOffA[lvl];
    const int tid = threadIdx.x;
    const float* ms = mscore + (size_t)b * TOTAL + lvlOff;
    const u64 CK = cutKey[b * 5 + lvl];
    if (tid == 0) sh_cnt = 0;
    __syncthreads();
    for (int i = tid; i < n; i += 512) {
        u64 key = (((u64)mapKm(ms[i])) << 32) | (u32)i;
        if (key <= CK) {
            int pos = atomicAdd(&sh_cnt, 1);
            if (pos < 1024) keys[pos] = key;
        }
    }
    __syncthreads();
    int M = sh_cnt; if (M > 1024) M = 1024;   // M == k (keys distinct, CK = k-th smallest)
    u64 k0 = (tid < M) ? keys[tid] : ~0ull;
    u64 k1 = (tid + 512 < M) ? keys[tid + 512] : ~0ull;
    int r0 = 0, r1 = 0;
    for (int f = 0; f < M; f++) {
        u64 kf = keys[f];
        r0 += (kf < k0);
        r1 += (kf < k1);
    }
    if (tid < M)
        writeCand(b, candA[lvl] + r0, k0, lvlOff, mscore, mlabel, anchors, reg,
                  cand_score, cand_box, cand_label);
    if (tid + 512 < M)
        writeCand(b, candA[lvl] + r1, k1, lvlOff, mscore, mlabel, anchors, reg,
                  cand_score, cand_box, cand_label);
}

// ---------------- Kernel 4 (fused): merge-by-rank + windowed greedy NMS + emit ----------------
__global__ void __launch_bounds__(1024) sort_nms(const float* __restrict__ cand_score,
                                                 const float* __restrict__ cand_box,
                                                 const int* __restrict__ cand_label,
                                                 float* __restrict__ out) {
    __shared__ __align__(16) char regA[53120];      // phase1: u64 keys[3320]; phase2: float4 bx[3320]
    __shared__ u16 sidx[NCAND];                     // rank -> cand index
    __shared__ u32 act32[NW32];
    __shared__ int sel[NDET];
    __shared__ u16 win[64];
    __shared__ float4 wb[64];
    __shared__ u64 wsup[64];
    __shared__ int s_nwin, s_count;
    __shared__ u64 s_accM;

    const int b = blockIdx.x, tid = threadIdx.x, nt = 1024;
    const int wave = tid >> 6, lane = tid & 63;
    const int segStart[5] = { 0, 1000, 2000, 3000, 3256 };
    const int segLen[5]   = { 1000, 1000, 1000, 256, 64 };

    u64* keys = (u64*)regA;
    float4* bx = (float4*)regA;

    for (int p = tid; p < NCAND; p += nt)
        keys[p] = makeKey(cand_score[b * NCAND + p], (u32)p);
    for (int i = tid; i < NW32; i += nt) act32[i] = 0;
    __syncthreads();

    // merge-by-rank: global rank = local rank + binary-search counts in other segments
    const u32 kmTHR = mapKm(STHR);
    for (int p = tid; p < NCAND; p += nt) {
        u64 K = keys[p];
        int lvl = (p < 1000) ? 0 : (p < 2000) ? 1 : (p < 3000) ? 2 : (p < 3256) ? 3 : 4;
        int rank = p - segStart[lvl];
#pragma unroll
        for (int s2 = 0; s2 < 5; s2++) {
            if (s2 == lvl) continue;
            int lo = 0, hi = segLen[s2], base = segStart[s2];
            while (lo < hi) {
                int mid = (lo + hi) >> 1;
                if (keys[base + mid] < K) lo = mid + 1; else hi = mid;
            }
            rank += lo;
        }
        sidx[rank] = (u16)p;
        if ((u32)(K >> 32) < kmTHR)
            atomicOr(&act32[rank >> 5], 1u << (rank & 31));
    }
    __syncthreads();

    // stage class-offset boxes in sorted order (overwrites keys region)
    for (int q = tid; q < NCAND; q += nt) {
        int p = sidx[q];
        float4 v = ((const float4*)cand_box)[b * NCAND + p];
        float off = (float)cand_label[b * NCAND + p] * (IMGSZ + 1.0f);
        v.x = __fadd_rn(v.x, off); v.y = __fadd_rn(v.y, off);
        v.z = __fadd_rn(v.z, off); v.w = __fadd_rn(v.w, off);
        bx[q] = v;
    }
    __syncthreads();

    // windowed greedy NMS
    int count = 0;
    while (true) {
        if (wave == 0) {
            u64 m = 0;
            if (lane < NWRD) m = (u64)act32[2 * lane] | ((u64)act32[2 * lane + 1] << 32);
            int c = __popcll(m);
            int incl = c;
            for (int o = 1; o < 64; o <<= 1) {
                int t = __shfl_up(incl, o);
                if (lane >= o) incl += t;
            }
            int pre = incl - c;
            int total = __shfl(incl, 63);
            int take = total < 64 ? total : 64;
            if (lane == 0) s_nwin = take;
            u64 mm = m; int r = 0;
            while (mm && (pre + r) < take) {
                int t = __builtin_ctzll(mm); mm &= mm - 1;
                win[pre + r] = (u16)(lane * 64 + t);
                r++;
            }
        }
        __syncthreads();
        const int nwin = s_nwin;
        if (nwin == 0) break;

        for (int t = tid; t < nwin; t += nt) wb[t] = bx[win[t]];
        __syncthreads();

#pragma unroll
        for (int kk = 0; kk < 4; kk++) {
            int r = wave + 16 * kk;
            bool sp = false;
            if (r < nwin && lane < nwin && lane > r) sp = suppress(wb[r], wb[lane]);
            u64 mask = __ballot(sp);
            if (lane == 0) wsup[r] = mask;
        }
        __syncthreads();

        if (wave == 0) {
            u64 supr = (lane < nwin) ? wsup[lane] : 0;
            u64 aliveM = (nwin >= 64) ? ~0ull : ((1ull << nwin) - 1ull);
            u64 accM = 0;
            for (int r = 0; r < nwin; r++) {
                if ((aliveM >> r) & 1) {
                    accM |= 1ull << r;
                    u64 sr = __shfl(supr, r);
                    aliveM &= ~sr;
                }
            }
            int na = __popcll(accM);
            int space = NDET - count;
            int takeA = na < space ? na : space;
            if (lane < nwin && ((accM >> lane) & 1)) {
                int pos = __popcll(accM & ((1ull << lane) - 1ull));
                if (pos < takeA) sel[count + pos] = (int)win[lane];
            }
            if (lane == 0) { s_count = count + takeA; s_accM = accM; }
        }
        __syncthreads();
        count = s_count;
        u64 accM = s_accM;
        if (count >= NDET) break;

        for (int t = tid; t < nwin; t += nt) {
            int q = win[t];
            atomicAnd(&act32[q >> 5], ~(1u << (q & 31)));
        }
        for (int j = tid; j < NCAND; j += nt) {
            if ((act32[j >> 5] >> (j & 31)) & 1) {
                float4 bj = bx[j];
                u64 am = accM;
                while (am) {
                    int r = __builtin_ctzll(am); am &= am - 1;
                    if (suppress(wb[r], bj)) {
                        atomicAnd(&act32[j >> 5], ~(1u << (j & 31)));
                        break;
                    }
                }
            }
        }
        __syncthreads();
    }
    __syncthreads();

    for (int s = tid; s < NDET; s += nt) {
        float4 bxv = make_float4(0.f, 0.f, 0.f, 0.f);
        float scv = 0.0f, lbv = -1.0f;
        if (s < count) {
            int ci = sidx[sel[s]];
            bxv = ((const float4*)cand_box)[b * NCAND + ci];
            scv = cand_score[b * NCAND + ci];
            lbv = (float)cand_label[b * NCAND + ci];
        }
        ((float4*)out)[b * NDET + s] = bxv;                                  // boxes [0,3200)
        out[BATCH * NDET * 4 + b * NDET + s] = scv;                          // scores [3200,4000)
        out[BATCH * NDET * 4 + BATCH * NDET + b * NDET + s] = lbv;           // labels [4000,4800)
    }
}

extern "C" void kernel_launch(void* const* d_in, const int* in_sizes, int n_in,
                              void* d_out, int out_size, void* d_ws, size_t ws_size,
                              hipStream_t stream) {
    (void)in_sizes; (void)n_in; (void)out_size; (void)ws_size;
    const float* logits  = (const float*)d_in[0];
    const float* reg     = (const float*)d_in[1];
    const float* ctr     = (const float*)d_in[2];
    const float* anchors = (const float*)d_in[3];
    float* out = (float*)d_out;

    char* ws = (char*)d_ws;
    size_t off = 0;
    auto alloc = [&](size_t bytes) -> void* {
        off = (off + 255) & ~(size_t)255;
        void* p = ws + off;
        off += bytes;
        return p;
    };
    u32*   hist   = (u32*)  alloc((size_t)BATCH * 5 * NBUCK * 4);
    float* mscore = (float*)alloc((size_t)BATCH * TOTAL * 4);
    int*   mlabel = (int*)  alloc((size_t)BATCH * TOTAL * 4);
    float* cscore = (float*)alloc((size_t)BATCH * NCAND * 4);
    float* cbox   = (float*)alloc((size_t)BATCH * NCAND * 16);
    int*   clabel = (int*)  alloc((size_t)BATCH * NCAND * 4);
    u64*   cutKey = (u64*)  alloc((size_t)BATCH * 5 * 8);

    hipMemsetAsync(hist, 0, (size_t)BATCH * 5 * NBUCK * 4, stream);
    score_kernel<<<dim3((TOTAL + 255) / 256, BATCH), 256, 0, stream>>>(logits, ctr, mscore, mlabel, hist);
    cutoff_kernel<<<BATCH * 5, 256, 0, stream>>>(mscore, hist, cutKey);
    place_kernel<<<BATCH * 5, 512, 0, stream>>>(mscore, mlabel, anchors, reg, cutKey,
                                                cscore, cbox, clabel);
    sort_nms<<<BATCH, 1024, 0, stream>>>(cscore, cbox, clabel, out);
}

// Round 6
// 224.543 us; speedup vs baseline: 3.0672x; 1.3438x over previous
//
#include <hip/hip_runtime.h>
#include <stdint.h>

typedef unsigned long long u64;
typedef unsigned int u32;
typedef unsigned short u16;

#define BATCH   8
#define TOTAL   21824
#define NCLS    80
#define NCAND   3320
#define NWRD    52          /* ceil(3320/64) */
#define NW32    104         /* ceil(3320/32) */
#define NDET    100
#define IMGSZ   1024.0f
#define STHR    0.2f
#define NMST    0.6f
#define NBUCK   65536       /* 16-bit buckets of km */

__device__ __forceinline__ float sigm(float x) { return 1.0f / (1.0f + expf(-x)); }

// Order-preserving map: ascending km == descending score.
__device__ __forceinline__ u32 mapKm(float s) {
    u32 u = __float_as_uint(s);
    u32 m = u ^ ((u & 0x80000000u) ? 0xFFFFFFFFu : 0x80000000u);
    return ~m;
}
// Composite sort key: ascending-u64 order == (score descending, index ascending).
__device__ __forceinline__ u64 makeKey(float s, u32 idx) {
    return (((u64)mapKm(s)) << 32) | (u64)idx;
}

// Bit-exact IoU suppression test (no FMA contraction) — must stay identical
// everywhere it is used so selection matches the numpy reference.
__device__ __forceinline__ bool suppress(float4 a, float4 c) {
    float aa = __fmul_rn(fmaxf(__fsub_rn(a.z, a.x), 0.f), fmaxf(__fsub_rn(a.w, a.y), 0.f));
    float ac = __fmul_rn(fmaxf(__fsub_rn(c.z, c.x), 0.f), fmaxf(__fsub_rn(c.w, c.y), 0.f));
    float ltx = fmaxf(a.x, c.x), lty = fmaxf(a.y, c.y);
    float rbx = fminf(a.z, c.z), rby = fminf(a.w, c.w);
    float iw = fmaxf(__fsub_rn(rbx, ltx), 0.f), ih = fmaxf(__fsub_rn(rby, lty), 0.f);
    float inter = __fmul_rn(iw, ih);
    float uni = __fsub_rn(__fadd_rn(aa, ac), inter);
    float iou = __fdiv_rn(inter, fmaxf(uni, 1e-9f));
    return iou > NMST;
}

// ---------------- Kernel 1: coalesced score/argmax + fused global histogram ----------------
__global__ __launch_bounds__(256) void score_kernel(
        const float* __restrict__ logits, const float* __restrict__ ctr,
        float* __restrict__ mscore, int* __restrict__ mlabel, u32* __restrict__ hist) {
    const int b = blockIdx.y;
    const int tid = threadIdx.x;
    const int wave = tid >> 6, lane = tid & 63;
    const int g = lane >> 2, j = lane & 3;
    const int rowBase = blockIdx.x * 256 + wave * 64;
#pragma unroll
    for (int t = 0; t < 4; t++) {
        int r = rowBase + 16 * t + g;
        bool valid = r < TOTAL;
        float best = -1e30f; int bi = 0;
        if (valid) {
            const float* rowp = logits + ((size_t)b * TOTAL + r) * NCLS + j * 4;
#pragma unroll
            for (int u = 0; u < 5; u++) {
                float4 v = *(const float4*)(rowp + u * 16);
                int c0 = u * 16 + j * 4;
                if (v.x > best) { best = v.x; bi = c0; }
                if (v.y > best) { best = v.y; bi = c0 + 1; }
                if (v.z > best) { best = v.z; bi = c0 + 2; }
                if (v.w > best) { best = v.w; bi = c0 + 3; }
            }
        }
        // merge 4 lanes of one row: max, tie -> lowest class index (first occurrence)
#pragma unroll
        for (int off = 1; off <= 2; off <<= 1) {
            float ob = __shfl_xor(best, off);
            int obi = __shfl_xor(bi, off);
            if (ob > best || (ob == best && obi < bi)) { best = ob; bi = obi; }
        }
        if (valid && j == 0) {
            float c = ctr[(size_t)b * TOTAL + r];
            float sc = sqrtf(sigm(best) * sigm(c));
            float msc = (sc > STHR) ? sc : -1.0f;
            mscore[(size_t)b * TOTAL + r] = msc;
            mlabel[(size_t)b * TOTAL + r] = bi;
            int lvl = (r < 16384) ? 0 : (r < 20480) ? 1 : (r < 21504) ? 2 : (r < 21760) ? 3 : 4;
            atomicAdd(&hist[(size_t)(b * 5 + lvl) * NBUCK + (mapKm(msc) >> 16)], 1u);
        }
    }
}

// ---------------- candidate decode+write ----------------
__device__ __forceinline__ void writeCand(int b, int pos, u64 key, int lvlOff,
                                          const float* mscore, const int* mlabel,
                                          const float* anchors, const float* reg,
                                          float* cand_score, float* cand_box, int* cand_label) {
    int li = (int)(key & 0xFFFFFFFFu);
    int g = lvlOff + li;
    size_t bg = (size_t)b * TOTAL + g;
    float sc = mscore[bg];
    int lb = mlabel[bg];
    float4 a = ((const float4*)anchors)[g];
    float4 r = ((const float4*)reg)[bg];
    float cx = (a.x + a.z) * 0.5f;
    float cy = (a.y + a.w) * 0.5f;
    float x1 = fminf(fmaxf(cx - r.x, 0.0f), IMGSZ);
    float y1 = fminf(fmaxf(cy - r.y, 0.0f), IMGSZ);
    float x2 = fminf(fmaxf(cx + r.z, 0.0f), IMGSZ);
    float y2 = fminf(fmaxf(cy + r.w, 0.0f), IMGSZ);
    int cp = b * NCAND + pos;
    cand_score[cp] = sc;
    cand_label[cp] = lb;
    ((float4*)cand_box)[cp] = make_float4(x1, y1, x2, y2);
}

// ---------------- Kernel 2 (fused): exact k-th key from histogram + gather/rank/write ----------------
__global__ __launch_bounds__(512) void select_kernel(
        const float* __restrict__ mscore, const int* __restrict__ mlabel,
        const float* __restrict__ anchors, const float* __restrict__ reg,
        const u32* __restrict__ hist, float* __restrict__ cand_score,
        float* __restrict__ cand_box, int* __restrict__ cand_label) {
    __shared__ u32 chunkSum[256];
    __shared__ int sh_chunk; __shared__ u32 sh_cbase;
    __shared__ u32 sh_B, sh_cless;
    __shared__ int sh_m, sh_cnt;
    __shared__ u64 sh_ck;
    __shared__ u64 cl[2048];
    __shared__ u64 keys[1024];

    const int lvl = blockIdx.x % 5, b = blockIdx.x / 5;
    const int lvlOffA[5] = { 0, 16384, 20480, 21504, 21760 };
    const int nA[5]      = { 16384, 4096, 1024, 256, 64 };
    const int kA[5]      = { 1000, 1000, 1000, 256, 64 };
    const int candA[5]   = { 0, 1000, 2000, 3000, 3256 };
    const int n = nA[lvl], lvlOff = lvlOffA[lvl]; const u32 k = (u32)kA[lvl];
    const int tid = threadIdx.x, wave = tid >> 6, lane = tid & 63;
    const u32* H = hist + (size_t)(b * 5 + lvl) * NBUCK;
    const float* ms = mscore + (size_t)b * TOTAL + lvlOff;

    // --- Phase A: exact k-th smallest composite key (cutKey) ---
    for (int c = wave; c < 256; c += 8) {
        u32 s = 0;
#pragma unroll
        for (int q = 0; q < 4; q++) s += H[c * 256 + q * 64 + lane];
        for (int o = 32; o > 0; o >>= 1) s += __shfl_down(s, o);
        if (lane == 0) chunkSum[c] = s;
    }
    __syncthreads();
    if (wave == 0) {
        u32 h4[4]; u32 s = 0;
#pragma unroll
        for (int q = 0; q < 4; q++) { h4[q] = chunkSum[4 * lane + q]; s += h4[q]; }
        u32 incl = s;
        for (int o = 1; o < 64; o <<= 1) { u32 t2 = __shfl_up(incl, o); if (lane >= o) incl += t2; }
        u32 base = incl - s;
#pragma unroll
        for (int q = 0; q < 4; q++) {
            u32 E = base; base += h4[q];
            if (E < k && k <= base) { sh_chunk = 4 * lane + q; sh_cbase = E; }
        }
    }
    __syncthreads();
    const int cstar = sh_chunk; const u32 cbase = sh_cbase;
    if (wave == 0) {
        uint4 hv = ((const uint4*)(H + cstar * 256))[lane];
        u32 s = hv.x + hv.y + hv.z + hv.w;
        u32 incl = s;
        for (int o = 1; o < 64; o <<= 1) { u32 t2 = __shfl_up(incl, o); if (lane >= o) incl += t2; }
        u32 base = cbase + incl - s;
        u32 hh[4] = { hv.x, hv.y, hv.z, hv.w };
#pragma unroll
        for (int q = 0; q < 4; q++) {
            u32 E = base; base += hh[q];
            if (E < k && k <= base) { sh_B = (u32)(cstar * 256 + 4 * lane + q); sh_cless = E; }
        }
    }
    if (tid == 0) sh_m = 0;
    __syncthreads();
    const u32 Bstar = sh_B, cless = sh_cless;
    const u32 need = k - cless;      // >= 1 by construction
    for (int i = tid; i < n; i += 512) {
        u32 km = mapKm(ms[i]);
        if ((km >> 16) == Bstar) {
            int pos = atomicAdd(&sh_m, 1);
            if (pos < 2048) cl[pos] = (((u64)km) << 32) | (u32)i;
        }
    }
    __syncthreads();
    int m = sh_m; if (m > 2048) m = 2048;
    {
        u64 own[4]; int rk[4]; int nown = 0;
        for (int p = tid; p < m; p += 512) { own[nown] = cl[p]; rk[nown] = 0; nown++; }
        for (int f = 0; f < m; f++) {
            u64 kf = cl[f];
            for (int q2 = 0; q2 < nown; q2++) rk[q2] += (kf < own[q2]);
        }
        for (int q2 = 0; q2 < nown; q2++)
            if ((u32)rk[q2] == need - 1) sh_ck = own[q2];
    }
    if (tid == 0) sh_cnt = 0;
    __syncthreads();

    // --- Phase B: gather keys <= cutKey (exactly k of them), rank, write candidates ---
    const u64 CK = sh_ck;
    for (int i = tid; i < n; i += 512) {
        u64 key = (((u64)mapKm(ms[i])) << 32) | (u32)i;
        if (key <= CK) {
            int pos = atomicAdd(&sh_cnt, 1);
            if (pos < 1024) keys[pos] = key;
        }
    }
    __syncthreads();
    int M = sh_cnt; if (M > 1024) M = 1024;   // M == k (keys distinct, CK exact)
    u64 k0 = (tid < M) ? keys[tid] : ~0ull;
    u64 k1 = (tid + 512 < M) ? keys[tid + 512] : ~0ull;
    int r0 = 0, r1 = 0;
    for (int f = 0; f < M; f++) {
        u64 kf = keys[f];
        r0 += (kf < k0);
        r1 += (kf < k1);
    }
    if (tid < M)
        writeCand(b, candA[lvl] + r0, k0, lvlOff, mscore, mlabel, anchors, reg,
                  cand_score, cand_box, cand_label);
    if (tid + 512 < M)
        writeCand(b, candA[lvl] + r1, k1, lvlOff, mscore, mlabel, anchors, reg,
                  cand_score, cand_box, cand_label);
}

// ---------------- Kernel 3 (fused): merge-by-rank + LAZY windowed greedy NMS + emit ----------------
__global__ void __launch_bounds__(1024) sort_nms(const float* __restrict__ cand_score,
                                                 const float* __restrict__ cand_box,
                                                 const int* __restrict__ cand_label,
                                                 float* __restrict__ out) {
    __shared__ __align__(16) char regA[53120];      // phase1: u64 keys[3320]; phase2: float4 bx[3320]
    __shared__ u16 sidx[NCAND];                     // rank -> cand index
    __shared__ u32 act32[NW32];                     // valid & not-yet-examined
    __shared__ int sel[NDET];
    __shared__ float4 accB[NDET];                   // accepted class-offset boxes
    __shared__ u16 win[64];
    __shared__ float4 wb[64];
    __shared__ u64 wsup[64];
    __shared__ u32 s_rej32[2];
    __shared__ int s_nwin, s_count;

    const int b = blockIdx.x, tid = threadIdx.x, nt = 1024;
    const int wave = tid >> 6, lane = tid & 63;
    const int segStart[5] = { 0, 1000, 2000, 3000, 3256 };
    const int segLen[5]   = { 1000, 1000, 1000, 256, 64 };

    u64* keys = (u64*)regA;
    float4* bx = (float4*)regA;

    for (int p = tid; p < NCAND; p += nt)
        keys[p] = makeKey(cand_score[b * NCAND + p], (u32)p);
    for (int i = tid; i < NW32; i += nt) act32[i] = 0;
    __syncthreads();

    // merge-by-rank: global rank = local rank + binary-search counts in other segments
    const u32 kmTHR = mapKm(STHR);
    for (int p = tid; p < NCAND; p += nt) {
        u64 K = keys[p];
        int lvl = (p < 1000) ? 0 : (p < 2000) ? 1 : (p < 3000) ? 2 : (p < 3256) ? 3 : 4;
        int rank = p - segStart[lvl];
#pragma unroll
        for (int s2 = 0; s2 < 5; s2++) {
            if (s2 == lvl) continue;
            int lo = 0, hi = segLen[s2], base = segStart[s2];
            while (lo < hi) {
                int mid = (lo + hi) >> 1;
                if (keys[base + mid] < K) lo = mid + 1; else hi = mid;
            }
            rank += lo;
        }
        sidx[rank] = (u16)p;
        if ((u32)(K >> 32) < kmTHR)
            atomicOr(&act32[rank >> 5], 1u << (rank & 31));
    }
    __syncthreads();

    // stage class-offset boxes in sorted order (overwrites keys region)
    for (int q = tid; q < NCAND; q += nt) {
        int p = sidx[q];
        float4 v = ((const float4*)cand_box)[b * NCAND + p];
        float off = (float)cand_label[b * NCAND + p] * (IMGSZ + 1.0f);
        v.x = __fadd_rn(v.x, off); v.y = __fadd_rn(v.y, off);
        v.z = __fadd_rn(v.z, off); v.w = __fadd_rn(v.w, off);
        bx[q] = v;
    }
    __syncthreads();

    // lazy windowed greedy NMS: examine 64 candidates/round; test them only
    // against the accepted set (reject phase) + intra-window pair masks.
    int count = 0;
    while (true) {
        if (wave == 0) {
            u64 m = 0;
            if (lane < NWRD) m = (u64)act32[2 * lane] | ((u64)act32[2 * lane + 1] << 32);
            int c = __popcll(m);
            int incl = c;
            for (int o = 1; o < 64; o <<= 1) {
                int t = __shfl_up(incl, o);
                if (lane >= o) incl += t;
            }
            int pre = incl - c;
            int total = __shfl(incl, 63);
            int take = total < 64 ? total : 64;
            if (lane == 0) s_nwin = take;
            u64 mm = m; int r = 0;
            while (mm && (pre + r) < take) {
                int t = __builtin_ctzll(mm); mm &= mm - 1;
                win[pre + r] = (u16)(lane * 64 + t);
                r++;
            }
        }
        __syncthreads();
        const int nwin = s_nwin;
        if (nwin == 0) break;

        // mark window rows examined; stage their boxes; reset reject mask
        for (int t = tid; t < nwin; t += nt) {
            int q = win[t];
            atomicAnd(&act32[q >> 5], ~(1u << (q & 31)));
            wb[t] = bx[q];
        }
        if (tid < 2) s_rej32[tid] = 0;
        __syncthreads();

        // reject phase: window row (lane) vs accepted set (strided by wave)
        {
            bool rej = false;
            if (lane < nwin) {
                for (int s2 = wave; s2 < count; s2 += 16) {
                    if (suppress(accB[s2], wb[lane])) { rej = true; break; }
                }
            }
            u64 mask = __ballot(rej);
            if (lane == 0 && mask) {
                u32 lo = (u32)mask, hi = (u32)(mask >> 32);
                if (lo) atomicOr(&s_rej32[0], lo);
                if (hi) atomicOr(&s_rej32[1], hi);
            }
        }
        // intra-window pair masks: wsup[r] bit c == (r suppresses c), c>r
#pragma unroll
        for (int kk = 0; kk < 4; kk++) {
            int r = wave + 16 * kk;
            bool sp = false;
            if (r < nwin && lane < nwin && lane > r) sp = suppress(wb[r], wb[lane]);
            u64 mask = __ballot(sp);
            if (lane == 0) wsup[r] = mask;
        }
        __syncthreads();

        // greedy resolve within window (wave 0, registers only)
        if (wave == 0) {
            u64 supr = (lane < nwin) ? wsup[lane] : 0;
            u64 rejM = (u64)s_rej32[0] | ((u64)s_rej32[1] << 32);
            u64 aliveM = ((nwin >= 64) ? ~0ull : ((1ull << nwin) - 1ull)) & ~rejM;
            u64 accM = 0;
            for (int r = 0; r < nwin; r++) {
                if ((aliveM >> r) & 1) {
                    accM |= 1ull << r;
                    u64 sr = __shfl(supr, r);
                    aliveM &= ~sr;
                }
            }
            int na = __popcll(accM);
            int space = NDET - count;
            int takeA = na < space ? na : space;
            if (lane < nwin && ((accM >> lane) & 1)) {
                int pos = __popcll(accM & ((1ull << lane) - 1ull));
                if (pos < takeA) {
                    sel[count + pos] = (int)win[lane];
                    accB[count + pos] = wb[lane];
                }
            }
            if (lane == 0) s_count = count + takeA;
        }
        __syncthreads();
        count = s_count;
        if (count >= NDET) break;
    }
    __syncthreads();

    for (int s = tid; s < NDET; s += nt) {
        float4 bxv = make_float4(0.f, 0.f, 0.f, 0.f);
        float scv = 0.0f, lbv = -1.0f;
        if (s < count) {
            int ci = sidx[sel[s]];
            bxv = ((const float4*)cand_box)[b * NCAND + ci];
            scv = cand_score[b * NCAND + ci];
            lbv = (float)cand_label[b * NCAND + ci];
        }
        ((float4*)out)[b * NDET + s] = bxv;                                  // boxes [0,3200)
        out[BATCH * NDET * 4 + b * NDET + s] = scv;                          // scores [3200,4000)
        out[BATCH * NDET * 4 + BATCH * NDET + b * NDET + s] = lbv;           // labels [4000,4800)
    }
}

extern "C" void kernel_launch(void* const* d_in, const int* in_sizes, int n_in,
                              void* d_out, int out_size, void* d_ws, size_t ws_size,
                              hipStream_t stream) {
    (void)in_sizes; (void)n_in; (void)out_size; (void)ws_size;
    const float* logits  = (const float*)d_in[0];
    const float* reg     = (const float*)d_in[1];
    const float* ctr     = (const float*)d_in[2];
    const float* anchors = (const float*)d_in[3];
    float* out = (float*)d_out;

    char* ws = (char*)d_ws;
    size_t off = 0;
    auto alloc = [&](size_t bytes) -> void* {
        off = (off + 255) & ~(size_t)255;
        void* p = ws + off;
        off += bytes;
        return p;
    };
    u32*   hist   = (u32*)  alloc((size_t)BATCH * 5 * NBUCK * 4);
    float* mscore = (float*)alloc((size_t)BATCH * TOTAL * 4);
    int*   mlabel = (int*)  alloc((size_t)BATCH * TOTAL * 4);
    float* cscore = (float*)alloc((size_t)BATCH * NCAND * 4);
    float* cbox   = (float*)alloc((size_t)BATCH * NCAND * 16);
    int*   clabel = (int*)  alloc((size_t)BATCH * NCAND * 4);

    hipMemsetAsync(hist, 0, (size_t)BATCH * 5 * NBUCK * 4, stream);
    score_kernel<<<dim3((TOTAL + 255) / 256, BATCH), 256, 0, stream>>>(logits, ctr, mscore, mlabel, hist);
    select_kernel<<<BATCH * 5, 512, 0, stream>>>(mscore, mlabel, anchors, reg, hist,
                                                 cscore, cbox, clabel);
    sort_nms<<<BATCH, 1024, 0, stream>>>(cscore, cbox, clabel, out);
}

// Round 7
// 179.865 us; speedup vs baseline: 3.8291x; 1.2484x over previous
//
#include <hip/hip_runtime.h>
#include <stdint.h>

typedef unsigned long long u64;
typedef unsigned int u32;
typedef unsigned short u16;

#define BATCH   8
#define TOTAL   21824
#define NCLS    80
#define NCAND   3320
#define NWRD    52          /* ceil(3320/64) */
#define NW32    104         /* ceil(3320/32) */
#define NDET    100
#define IMGSZ   1024.0f
#define STHR    0.2f
#define NMST    0.6f
#define NBUCK   2048        /* monotone score buckets */

__device__ __forceinline__ float sigm(float x) { return 1.0f / (1.0f + expf(-x)); }

// Order-preserving map: ascending km == descending score.
__device__ __forceinline__ u32 mapKm(float s) {
    u32 u = __float_as_uint(s);
    u32 m = u ^ ((u & 0x80000000u) ? 0xFFFFFFFFu : 0x80000000u);
    return ~m;
}
// Composite sort key: ascending-u64 order == (score descending, index ascending).
__device__ __forceinline__ u64 makeKey(float s, u32 idx) {
    return (((u64)mapKm(s)) << 32) | (u64)idx;
}

// Monotone bucket: descending score -> ascending bucket. Exact IEEE ops so the
// same value maps identically in score_kernel and select_kernel. Valid scores
// (0.2,1.0] land in [0,2016); masked -1.0 lands at 5040 -> clamped 2047.
__device__ __forceinline__ int bucketOf(float s) {
    int b = (int)(__fmul_rn(__fsub_rn(1.0f, s), 2520.0f));
    return b > (NBUCK - 1) ? (NBUCK - 1) : b;
}

// Bit-exact IoU suppression test (no FMA contraction).
__device__ __forceinline__ bool suppress(float4 a, float4 c) {
    float aa = __fmul_rn(fmaxf(__fsub_rn(a.z, a.x), 0.f), fmaxf(__fsub_rn(a.w, a.y), 0.f));
    float ac = __fmul_rn(fmaxf(__fsub_rn(c.z, c.x), 0.f), fmaxf(__fsub_rn(c.w, c.y), 0.f));
    float ltx = fmaxf(a.x, c.x), lty = fmaxf(a.y, c.y);
    float rbx = fminf(a.z, c.z), rby = fminf(a.w, c.w);
    float iw = fmaxf(__fsub_rn(rbx, ltx), 0.f), ih = fmaxf(__fsub_rn(rby, lty), 0.f);
    float inter = __fmul_rn(iw, ih);
    float uni = __fsub_rn(__fadd_rn(aa, ac), inter);
    float iou = __fdiv_rn(inter, fmaxf(uni, 1e-9f));
    return iou > NMST;
}

// ---------------- Kernel 1: coalesced score/argmax + fused bucket histogram ----------------
__global__ __launch_bounds__(256) void score_kernel(
        const float* __restrict__ logits, const float* __restrict__ ctr,
        float* __restrict__ mscore, int* __restrict__ mlabel, u32* __restrict__ hist) {
    const int b = blockIdx.y;
    const int tid = threadIdx.x;
    const int wave = tid >> 6, lane = tid & 63;
    const int g = lane >> 2, j = lane & 3;
    const int rowBase = blockIdx.x * 256 + wave * 64;
#pragma unroll
    for (int t = 0; t < 4; t++) {
        int r = rowBase + 16 * t + g;
        bool valid = r < TOTAL;
        float best = -1e30f; int bi = 0;
        if (valid) {
            const float* rowp = logits + ((size_t)b * TOTAL + r) * NCLS + j * 4;
#pragma unroll
            for (int u = 0; u < 5; u++) {
                float4 v = *(const float4*)(rowp + u * 16);
                int c0 = u * 16 + j * 4;
                if (v.x > best) { best = v.x; bi = c0; }
                if (v.y > best) { best = v.y; bi = c0 + 1; }
                if (v.z > best) { best = v.z; bi = c0 + 2; }
                if (v.w > best) { best = v.w; bi = c0 + 3; }
            }
        }
        // merge 4 lanes of one row: max, tie -> lowest class index
#pragma unroll
        for (int off = 1; off <= 2; off <<= 1) {
            float ob = __shfl_xor(best, off);
            int obi = __shfl_xor(bi, off);
            if (ob > best || (ob == best && obi < bi)) { best = ob; bi = obi; }
        }
        if (valid && j == 0) {
            float c = ctr[(size_t)b * TOTAL + r];
            float sc = sqrtf(sigm(best) * sigm(c));
            float msc = (sc > STHR) ? sc : -1.0f;
            mscore[(size_t)b * TOTAL + r] = msc;
            mlabel[(size_t)b * TOTAL + r] = bi;
            int lvl = (r < 16384) ? 0 : (r < 20480) ? 1 : (r < 21504) ? 2 : (r < 21760) ? 3 : 4;
            atomicAdd(&hist[(b * 5 + lvl) * NBUCK + bucketOf(msc)], 1u);
        }
    }
}

// ---------------- candidate decode+write ----------------
__device__ __forceinline__ void writeCand(int b, int pos, u64 key, int lvlOff,
                                          const float* mscore, const int* mlabel,
                                          const float* anchors, const float* reg,
                                          float* cand_score, float* cand_box, int* cand_label) {
    int li = (int)(key & 0xFFFFFFFFu);
    int g = lvlOff + li;
    size_t bg = (size_t)b * TOTAL + g;
    float sc = mscore[bg];
    int lb = mlabel[bg];
    float4 a = ((const float4*)anchors)[g];
    float4 r = ((const float4*)reg)[bg];
    float cx = (a.x + a.z) * 0.5f;
    float cy = (a.y + a.w) * 0.5f;
    float x1 = fminf(fmaxf(cx - r.x, 0.0f), IMGSZ);
    float y1 = fminf(fmaxf(cy - r.y, 0.0f), IMGSZ);
    float x2 = fminf(fmaxf(cx + r.z, 0.0f), IMGSZ);
    float y2 = fminf(fmaxf(cy + r.w, 0.0f), IMGSZ);
    int cp = b * NCAND + pos;
    cand_score[cp] = sc;
    cand_label[cp] = lb;
    ((float4*)cand_box)[cp] = make_float4(x1, y1, x2, y2);
}

// ---------------- Kernel 2: histogram scan -> boundary bucket -> single-pass gather/rank ----------------
__global__ __launch_bounds__(512) void select_kernel(
        const float* __restrict__ mscore, const int* __restrict__ mlabel,
        const float* __restrict__ anchors, const float* __restrict__ reg,
        const u32* __restrict__ hist, float* __restrict__ cand_score,
        float* __restrict__ cand_box, int* __restrict__ cand_label) {
    __shared__ u32 waveSum[8], waveOff[8];
    __shared__ u32 sh_B, sh_cless;
    __shared__ int sh_m, sh_cnt;
    __shared__ u64 cl[2048];
    __shared__ u64 keys[1024];

    const int lvl = blockIdx.x % 5, b = blockIdx.x / 5;
    const int lvlOffA[5] = { 0, 16384, 20480, 21504, 21760 };
    const int nA[5]      = { 16384, 4096, 1024, 256, 64 };
    const int kA[5]      = { 1000, 1000, 1000, 256, 64 };
    const int candA[5]   = { 0, 1000, 2000, 3000, 3256 };
    const int n = nA[lvl], lvlOff = lvlOffA[lvl]; const u32 k = (u32)kA[lvl];
    const int tid = threadIdx.x, wave = tid >> 6, lane = tid & 63;
    const u32* H = hist + (b * 5 + lvl) * NBUCK;
    const float* ms = mscore + (size_t)b * TOTAL + lvlOff;

    // --- Phase A: block scan of 2048-bucket histogram; locate boundary bucket ---
    uint4 hv = ((const uint4*)H)[tid];          // thread t owns buckets 4t..4t+3
    u32 s = hv.x + hv.y + hv.z + hv.w;
    u32 incl = s;
    for (int o = 1; o < 64; o <<= 1) {
        u32 t2 = (u32)__shfl_up((int)incl, o);
        if (lane >= o) incl += t2;
    }
    if (lane == 63) waveSum[wave] = incl;
    __syncthreads();
    if (tid == 0) {
        u32 acc = 0;
#pragma unroll
        for (int w = 0; w < 8; w++) { waveOff[w] = acc; acc += waveSum[w]; }
    }
    if (tid == 0) { sh_m = 0; sh_cnt = 0; }
    __syncthreads();
    {
        u32 base = waveOff[wave] + incl - s;    // keys in buckets < 4*tid
        u32 hh[4] = { hv.x, hv.y, hv.z, hv.w };
#pragma unroll
        for (int q = 0; q < 4; q++) {
            u32 E = base; base += hh[q];
            if (E < k && k <= base) { sh_B = (u32)(4 * tid + q); sh_cless = E; }
        }
    }
    __syncthreads();
    const int Bstar = (int)sh_B;
    const u32 need = k - sh_cless;              // >= 1 by construction

    // --- Phase B: one pass over level scores; below-boundary -> keys, boundary -> cl ---
    for (int i = tid; i < n; i += 512) {
        float sv = ms[i];
        int bk = bucketOf(sv);
        if (bk < Bstar) {
            int pos = atomicAdd(&sh_cnt, 1);
            keys[pos] = makeKey(sv, (u32)i);    // exactly sh_cless < k entries
        } else if (bk == Bstar) {
            int pos = atomicAdd(&sh_m, 1);
            if (pos < 2048) cl[pos] = makeKey(sv, (u32)i);
        }
    }
    __syncthreads();
    int m = sh_m; if (m > 2048) m = 2048;
    // rank boundary members exactly; append the `need` smallest to keys
    {
        u64 own[4]; int rk[4]; int nown = 0;
        for (int p = tid; p < m; p += 512) { own[nown] = cl[p]; rk[nown] = 0; nown++; }
        for (int f = 0; f < m; f++) {
            u64 kf = cl[f];
            for (int q2 = 0; q2 < nown; q2++) rk[q2] += (kf < own[q2]);
        }
        for (int q2 = 0; q2 < nown; q2++) {
            if ((u32)rk[q2] < need) {
                int pos = atomicAdd(&sh_cnt, 1);
                keys[pos] = own[q2];
            }
        }
    }
    __syncthreads();
    const int M = sh_cnt;                        // == k exactly
    // rank the k candidates (broadcast LDS reads) and write by rank
    u64 k0 = (tid < M) ? keys[tid] : ~0ull;
    u64 k1 = (tid + 512 < M) ? keys[tid + 512] : ~0ull;
    int r0 = 0, r1 = 0;
    for (int f = 0; f < M; f++) {
        u64 kf = keys[f];
        r0 += (kf < k0);
        r1 += (kf < k1);
    }
    if (tid < M)
        writeCand(b, candA[lvl] + r0, k0, lvlOff, mscore, mlabel, anchors, reg,
                  cand_score, cand_box, cand_label);
    if (tid + 512 < M)
        writeCand(b, candA[lvl] + r1, k1, lvlOff, mscore, mlabel, anchors, reg,
                  cand_score, cand_box, cand_label);
}

// ---------------- Kernel 3 (fused): merge-by-rank + LAZY windowed greedy NMS + emit ----------------
__global__ void __launch_bounds__(1024) sort_nms(const float* __restrict__ cand_score,
                                                 const float* __restrict__ cand_box,
                                                 const int* __restrict__ cand_label,
                                                 float* __restrict__ out) {
    __shared__ __align__(16) char regA[53120];      // phase1: u64 keys[3320]; phase2: float4 bx[3320]
    __shared__ u16 sidx[NCAND];                     // rank -> cand index
    __shared__ u32 act32[NW32];                     // valid & not-yet-examined
    __shared__ int sel[NDET];
    __shared__ float4 accB[NDET];                   // accepted class-offset boxes
    __shared__ u16 win[64];
    __shared__ float4 wb[64];
    __shared__ u64 wsup[64];
    __shared__ u32 s_rej32[2];
    __shared__ int s_nwin, s_count;

    const int b = blockIdx.x, tid = threadIdx.x, nt = 1024;
    const int wave = tid >> 6, lane = tid & 63;
    const int segStart[5] = { 0, 1000, 2000, 3000, 3256 };
    const int segLen[5]   = { 1000, 1000, 1000, 256, 64 };

    u64* keys = (u64*)regA;
    float4* bx = (float4*)regA;

    for (int p = tid; p < NCAND; p += nt)
        keys[p] = makeKey(cand_score[b * NCAND + p], (u32)p);
    for (int i = tid; i < NW32; i += nt) act32[i] = 0;
    __syncthreads();

    // merge-by-rank: global rank = local rank + binary-search counts in other segments
    const u32 kmTHR = mapKm(STHR);
    for (int p = tid; p < NCAND; p += nt) {
        u64 K = keys[p];
        int lvl = (p < 1000) ? 0 : (p < 2000) ? 1 : (p < 3000) ? 2 : (p < 3256) ? 3 : 4;
        int rank = p - segStart[lvl];
#pragma unroll
        for (int s2 = 0; s2 < 5; s2++) {
            if (s2 == lvl) continue;
            int lo = 0, hi = segLen[s2], base = segStart[s2];
            while (lo < hi) {
                int mid = (lo + hi) >> 1;
                if (keys[base + mid] < K) lo = mid + 1; else hi = mid;
            }
            rank += lo;
        }
        sidx[rank] = (u16)p;
        if ((u32)(K >> 32) < kmTHR)
            atomicOr(&act32[rank >> 5], 1u << (rank & 31));
    }
    __syncthreads();

    // stage class-offset boxes in sorted order (overwrites keys region)
    for (int q = tid; q < NCAND; q += nt) {
        int p = sidx[q];
        float4 v = ((const float4*)cand_box)[b * NCAND + p];
        float off = (float)cand_label[b * NCAND + p] * (IMGSZ + 1.0f);
        v.x = __fadd_rn(v.x, off); v.y = __fadd_rn(v.y, off);
        v.z = __fadd_rn(v.z, off); v.w = __fadd_rn(v.w, off);
        bx[q] = v;
    }
    __syncthreads();

    // lazy windowed greedy NMS
    int count = 0;
    while (true) {
        if (wave == 0) {
            u64 m = 0;
            if (lane < NWRD) m = (u64)act32[2 * lane] | ((u64)act32[2 * lane + 1] << 32);
            int c = __popcll(m);
            int incl = c;
            for (int o = 1; o < 64; o <<= 1) {
                int t = __shfl_up(incl, o);
                if (lane >= o) incl += t;
            }
            int pre = incl - c;
            int total = __shfl(incl, 63);
            int take = total < 64 ? total : 64;
            if (lane == 0) s_nwin = take;
            u64 mm = m; int r = 0;
            while (mm && (pre + r) < take) {
                int t = __builtin_ctzll(mm); mm &= mm - 1;
                win[pre + r] = (u16)(lane * 64 + t);
                r++;
            }
        }
        __syncthreads();
        const int nwin = s_nwin;
        if (nwin == 0) break;

        for (int t = tid; t < nwin; t += nt) {
            int q = win[t];
            atomicAnd(&act32[q >> 5], ~(1u << (q & 31)));
            wb[t] = bx[q];
        }
        if (tid < 2) s_rej32[tid] = 0;
        __syncthreads();

        // reject phase: window row (lane) vs accepted set (strided by wave)
        {
            bool rej = false;
            if (lane < nwin) {
                for (int s2 = wave; s2 < count; s2 += 16) {
                    if (suppress(accB[s2], wb[lane])) { rej = true; break; }
                }
            }
            u64 mask = __ballot(rej);
            if (lane == 0 && mask) {
                u32 lo = (u32)mask, hi = (u32)(mask >> 32);
                if (lo) atomicOr(&s_rej32[0], lo);
                if (hi) atomicOr(&s_rej32[1], hi);
            }
        }
        // intra-window pair masks: wsup[r] bit c == (r suppresses c), c>r
#pragma unroll
        for (int kk = 0; kk < 4; kk++) {
            int r = wave + 16 * kk;
            bool sp = false;
            if (r < nwin && lane < nwin && lane > r) sp = suppress(wb[r], wb[lane]);
            u64 mask = __ballot(sp);
            if (lane == 0) wsup[r] = mask;
        }
        __syncthreads();

        if (wave == 0) {
            u64 supr = (lane < nwin) ? wsup[lane] : 0;
            u64 rejM = (u64)s_rej32[0] | ((u64)s_rej32[1] << 32);
            u64 aliveM = ((nwin >= 64) ? ~0ull : ((1ull << nwin) - 1ull)) & ~rejM;
            u64 accM = 0;
            for (int r = 0; r < nwin; r++) {
                if ((aliveM >> r) & 1) {
                    accM |= 1ull << r;
                    u64 sr = __shfl(supr, r);
                    aliveM &= ~sr;
                }
            }
            int na = __popcll(accM);
            int space = NDET - count;
            int takeA = na < space ? na : space;
            if (lane < nwin && ((accM >> lane) & 1)) {
                int pos = __popcll(accM & ((1ull << lane) - 1ull));
                if (pos < takeA) {
                    sel[count + pos] = (int)win[lane];
                    accB[count + pos] = wb[lane];
                }
            }
            if (lane == 0) s_count = count + takeA;
        }
        __syncthreads();
        count = s_count;
        if (count >= NDET) break;
    }
    __syncthreads();

    for (int s = tid; s < NDET; s += nt) {
        float4 bxv = make_float4(0.f, 0.f, 0.f, 0.f);
        float scv = 0.0f, lbv = -1.0f;
        if (s < count) {
            int ci = sidx[sel[s]];
            bxv = ((const float4*)cand_box)[b * NCAND + ci];
            scv = cand_score[b * NCAND + ci];
            lbv = (float)cand_label[b * NCAND + ci];
        }
        ((float4*)out)[b * NDET + s] = bxv;                                  // boxes [0,3200)
        out[BATCH * NDET * 4 + b * NDET + s] = scv;                          // scores [3200,4000)
        out[BATCH * NDET * 4 + BATCH * NDET + b * NDET + s] = lbv;           // labels [4000,4800)
    }
}

extern "C" void kernel_launch(void* const* d_in, const int* in_sizes, int n_in,
                              void* d_out, int out_size, void* d_ws, size_t ws_size,
                              hipStream_t stream) {
    (void)in_sizes; (void)n_in; (void)out_size; (void)ws_size;
    const float* logits  = (const float*)d_in[0];
    const float* reg     = (const float*)d_in[1];
    const float* ctr     = (const float*)d_in[2];
    const float* anchors = (const float*)d_in[3];
    float* out = (float*)d_out;

    char* ws = (char*)d_ws;
    size_t off = 0;
    auto alloc = [&](size_t bytes) -> void* {
        off = (off + 255) & ~(size_t)255;
        void* p = ws + off;
        off += bytes;
        return p;
    };
    u32*   hist   = (u32*)  alloc((size_t)BATCH * 5 * NBUCK * 4);
    float* mscore = (float*)alloc((size_t)BATCH * TOTAL * 4);
    int*   mlabel = (int*)  alloc((size_t)BATCH * TOTAL * 4);
    float* cscore = (float*)alloc((size_t)BATCH * NCAND * 4);
    float* cbox   = (float*)alloc((size_t)BATCH * NCAND * 16);
    int*   clabel = (int*)  alloc((size_t)BATCH * NCAND * 4);

    hipMemsetAsync(hist, 0, (size_t)BATCH * 5 * NBUCK * 4, stream);
    score_kernel<<<dim3((TOTAL + 255) / 256, BATCH), 256, 0, stream>>>(logits, ctr, mscore, mlabel, hist);
    select_kernel<<<BATCH * 5, 512, 0, stream>>>(mscore, mlabel, anchors, reg, hist,
                                                 cscore, cbox, clabel);
    sort_nms<<<BATCH, 1024, 0, stream>>>(cscore, cbox, clabel, out);
}

// Round 8
// 173.034 us; speedup vs baseline: 3.9803x; 1.0395x over previous
//
#include <hip/hip_runtime.h>
#include <stdint.h>

typedef unsigned long long u64;
typedef unsigned int u32;
typedef unsigned short u16;

#define BATCH   8
#define TOTAL   21824
#define NCLS    80
#define NCAND   3320
#define NDET    100
#define IMGSZ   1024.0f
#define STHR    0.2f
#define NMST    0.6f
#define NBUCK   2048        /* monotone score buckets */

__device__ __forceinline__ float sigm(float x) { return 1.0f / (1.0f + expf(-x)); }

// Order-preserving map: ascending km == descending score.
__device__ __forceinline__ u32 mapKm(float s) {
    u32 u = __float_as_uint(s);
    u32 m = u ^ ((u & 0x80000000u) ? 0xFFFFFFFFu : 0x80000000u);
    return ~m;
}
// Composite sort key: ascending-u64 order == (score descending, index ascending).
__device__ __forceinline__ u64 makeKey(float s, u32 idx) {
    return (((u64)mapKm(s)) << 32) | (u64)idx;
}

// Monotone bucket: descending score -> ascending bucket. Exact IEEE ops so the
// same value maps identically in score_kernel and select_kernel.
__device__ __forceinline__ int bucketOf(float s) {
    int b = (int)(__fmul_rn(__fsub_rn(1.0f, s), 2520.0f));
    return b > (NBUCK - 1) ? (NBUCK - 1) : b;
}

// Bit-exact IoU suppression test (no FMA contraction).
__device__ __forceinline__ bool suppress(float4 a, float4 c) {
    float aa = __fmul_rn(fmaxf(__fsub_rn(a.z, a.x), 0.f), fmaxf(__fsub_rn(a.w, a.y), 0.f));
    float ac = __fmul_rn(fmaxf(__fsub_rn(c.z, c.x), 0.f), fmaxf(__fsub_rn(c.w, c.y), 0.f));
    float ltx = fmaxf(a.x, c.x), lty = fmaxf(a.y, c.y);
    float rbx = fminf(a.z, c.z), rby = fminf(a.w, c.w);
    float iw = fmaxf(__fsub_rn(rbx, ltx), 0.f), ih = fmaxf(__fsub_rn(rby, lty), 0.f);
    float inter = __fmul_rn(iw, ih);
    float uni = __fsub_rn(__fadd_rn(aa, ac), inter);
    float iou = __fdiv_rn(inter, fmaxf(uni, 1e-9f));
    return iou > NMST;
}

// ---------------- Kernel 1: coalesced score/argmax + LDS-hist (level-uniform blocks) ----------------
__global__ __launch_bounds__(256) void score_kernel(
        const float* __restrict__ logits, const float* __restrict__ ctr,
        float* __restrict__ mscore, int* __restrict__ mlabel, u32* __restrict__ hist) {
    __shared__ u32 lh[NBUCK];
    const int b = blockIdx.y;
    const int tid = threadIdx.x;
    const int wave = tid >> 6, lane = tid & 63;
    const int g = lane >> 2, j = lane & 3;
    const int rowBase = blockIdx.x * 256 + wave * 64;
    for (int i = tid; i < NBUCK; i += 256) lh[i] = 0;
    __syncthreads();
#pragma unroll
    for (int t = 0; t < 4; t++) {
        int r = rowBase + 16 * t + g;
        bool valid = r < TOTAL;
        float best = -1e30f; int bi = 0;
        if (valid) {
            const float* rowp = logits + ((size_t)b * TOTAL + r) * NCLS + j * 4;
#pragma unroll
            for (int u = 0; u < 5; u++) {
                float4 v = *(const float4*)(rowp + u * 16);
                int c0 = u * 16 + j * 4;
                if (v.x > best) { best = v.x; bi = c0; }
                if (v.y > best) { best = v.y; bi = c0 + 1; }
                if (v.z > best) { best = v.z; bi = c0 + 2; }
                if (v.w > best) { best = v.w; bi = c0 + 3; }
            }
        }
        // merge 4 lanes of one row: max, tie -> lowest class index
#pragma unroll
        for (int off = 1; off <= 2; off <<= 1) {
            float ob = __shfl_xor(best, off);
            int obi = __shfl_xor(bi, off);
            if (ob > best || (ob == best && obi < bi)) { best = ob; bi = obi; }
        }
        if (valid && j == 0) {
            float c = ctr[(size_t)b * TOTAL + r];
            float sc = sqrtf(sigm(best) * sigm(c));
            float msc = (sc > STHR) ? sc : -1.0f;
            mscore[(size_t)b * TOTAL + r] = msc;
            mlabel[(size_t)b * TOTAL + r] = bi;
            atomicAdd(&lh[bucketOf(msc)], 1u);
        }
    }
    __syncthreads();
    // level boundaries (16384,20480,21504,21760) are multiples of 256 -> block is level-uniform
    const int fr = blockIdx.x * 256;
    const int lvl = (fr < 16384) ? 0 : (fr < 20480) ? 1 : (fr < 21504) ? 2 : (fr < 21760) ? 3 : 4;
    u32* Hd = hist + (b * 5 + lvl) * NBUCK;
    for (int i = tid; i < NBUCK; i += 256) {
        u32 v = lh[i];
        if (v) atomicAdd(&Hd[i], v);
    }
}

// ---------------- candidate decode+write ----------------
__device__ __forceinline__ void writeCand(int b, int pos, u64 key, int lvlOff,
                                          const float* mscore, const int* mlabel,
                                          const float* anchors, const float* reg,
                                          float* cand_score, float* cand_box, int* cand_label) {
    int li = (int)(key & 0xFFFFFFFFu);
    int g = lvlOff + li;
    size_t bg = (size_t)b * TOTAL + g;
    float sc = mscore[bg];
    int lb = mlabel[bg];
    float4 a = ((const float4*)anchors)[g];
    float4 r = ((const float4*)reg)[bg];
    float cx = (a.x + a.z) * 0.5f;
    float cy = (a.y + a.w) * 0.5f;
    float x1 = fminf(fmaxf(cx - r.x, 0.0f), IMGSZ);
    float y1 = fminf(fmaxf(cy - r.y, 0.0f), IMGSZ);
    float x2 = fminf(fmaxf(cx + r.z, 0.0f), IMGSZ);
    float y2 = fminf(fmaxf(cy + r.w, 0.0f), IMGSZ);
    int cp = b * NCAND + pos;
    cand_score[cp] = sc;
    cand_label[cp] = lb;
    ((float4*)cand_box)[cp] = make_float4(x1, y1, x2, y2);
}

// ---------------- Kernel 2: histogram scan -> boundary bucket -> single-pass gather/rank ----------------
__global__ __launch_bounds__(512) void select_kernel(
        const float* __restrict__ mscore, const int* __restrict__ mlabel,
        const float* __restrict__ anchors, const float* __restrict__ reg,
        const u32* __restrict__ hist, float* __restrict__ cand_score,
        float* __restrict__ cand_box, int* __restrict__ cand_label) {
    __shared__ u32 waveSum[8], waveOff[8];
    __shared__ u32 sh_B, sh_cless;
    __shared__ int sh_m, sh_cnt;
    __shared__ u64 cl[2048];
    __shared__ u64 keys[1024];

    const int lvl = blockIdx.x % 5, b = blockIdx.x / 5;
    const int lvlOffA[5] = { 0, 16384, 20480, 21504, 21760 };
    const int nA[5]      = { 16384, 4096, 1024, 256, 64 };
    const int kA[5]      = { 1000, 1000, 1000, 256, 64 };
    const int candA[5]   = { 0, 1000, 2000, 3000, 3256 };
    const int n = nA[lvl], lvlOff = lvlOffA[lvl]; const u32 k = (u32)kA[lvl];
    const int tid = threadIdx.x, wave = tid >> 6, lane = tid & 63;
    const u32* H = hist + (b * 5 + lvl) * NBUCK;
    const float* ms = mscore + (size_t)b * TOTAL + lvlOff;

    // --- Phase A: block scan of 2048-bucket histogram; locate boundary bucket ---
    uint4 hv = ((const uint4*)H)[tid];          // thread t owns buckets 4t..4t+3
    u32 s = hv.x + hv.y + hv.z + hv.w;
    u32 incl = s;
    for (int o = 1; o < 64; o <<= 1) {
        u32 t2 = (u32)__shfl_up((int)incl, o);
        if (lane >= o) incl += t2;
    }
    if (lane == 63) waveSum[wave] = incl;
    __syncthreads();
    if (tid == 0) {
        u32 acc = 0;
#pragma unroll
        for (int w = 0; w < 8; w++) { waveOff[w] = acc; acc += waveSum[w]; }
        sh_m = 0; sh_cnt = 0;
    }
    __syncthreads();
    {
        u32 base = waveOff[wave] + incl - s;
        u32 hh[4] = { hv.x, hv.y, hv.z, hv.w };
#pragma unroll
        for (int q = 0; q < 4; q++) {
            u32 E = base; base += hh[q];
            if (E < k && k <= base) { sh_B = (u32)(4 * tid + q); sh_cless = E; }
        }
    }
    __syncthreads();
    const int Bstar = (int)sh_B;
    const u32 need = k - sh_cless;

    // --- Phase B: one pass; below-boundary -> keys, boundary -> cl ---
    for (int i = tid; i < n; i += 512) {
        float sv = ms[i];
        int bk = bucketOf(sv);
        if (bk < Bstar) {
            int pos = atomicAdd(&sh_cnt, 1);
            keys[pos] = makeKey(sv, (u32)i);
        } else if (bk == Bstar) {
            int pos = atomicAdd(&sh_m, 1);
            if (pos < 2048) cl[pos] = makeKey(sv, (u32)i);
        }
    }
    __syncthreads();
    int m = sh_m; if (m > 2048) m = 2048;
    {
        u64 own[4]; int rk[4]; int nown = 0;
        for (int p = tid; p < m; p += 512) { own[nown] = cl[p]; rk[nown] = 0; nown++; }
        for (int f = 0; f < m; f++) {
            u64 kf = cl[f];
            for (int q2 = 0; q2 < nown; q2++) rk[q2] += (kf < own[q2]);
        }
        for (int q2 = 0; q2 < nown; q2++) {
            if ((u32)rk[q2] < need) {
                int pos = atomicAdd(&sh_cnt, 1);
                keys[pos] = own[q2];
            }
        }
    }
    __syncthreads();
    const int M = sh_cnt;                        // == k exactly
    u64 k0 = (tid < M) ? keys[tid] : ~0ull;
    u64 k1 = (tid + 512 < M) ? keys[tid + 512] : ~0ull;
    int r0 = 0, r1 = 0;
    for (int f = 0; f < M; f++) {
        u64 kf = keys[f];
        r0 += (kf < k0);
        r1 += (kf < k1);
    }
    if (tid < M)
        writeCand(b, candA[lvl] + r0, k0, lvlOff, mscore, mlabel, anchors, reg,
                  cand_score, cand_box, cand_label);
    if (tid + 512 < M)
        writeCand(b, candA[lvl] + r1, k1, lvlOff, mscore, mlabel, anchors, reg,
                  cand_score, cand_box, cand_label);
}

// ---------------- Kernel 3: lazy 5-way merge + windowed greedy NMS + emit ----------------
// Pool = next <=64 keys per sorted segment (wave w loads segment w, coalesced).
// The take=min(64,V) smallest valid pool keys are exactly the next `take`
// candidates in global (score desc, idx asc) order. No full sort ever built.
__global__ void __launch_bounds__(320) nms_kernel(const float* __restrict__ cand_score,
                                                  const float* __restrict__ cand_box,
                                                  const int* __restrict__ cand_label,
                                                  float* __restrict__ out) {
    __shared__ u64 poolKey[320];
    __shared__ int h[5], cons[5];
    __shared__ int sel[NDET];
    __shared__ float4 accB[NDET];
    __shared__ int winP[64];
    __shared__ float4 wb[64];
    __shared__ u64 wsup[64];
    __shared__ u32 s_rej32[2];
    __shared__ int s_take, s_count;

    const int b = blockIdx.x, tid = threadIdx.x;
    const int wave = tid >> 6, lane = tid & 63;   // wave == segment for pool load
    const int segBase[5] = { 0, 1000, 2000, 3000, 3256 };
    const int segLen[5]  = { 1000, 1000, 1000, 256, 64 };
    const u64 KTHR = ((u64)mapKm(STHR)) << 32;    // keys >= KTHR are invalid (score <= STHR)

    if (tid < 5) { h[tid] = 0; cons[tid] = 0; }
    if (tid == 0) s_count = 0;
    __syncthreads();

    int count = 0;
    while (true) {
        // 1) load pool: wave w takes segment w's next <=64 keys
        {
            int hs = h[wave];
            int rem = segLen[wave] - hs;
            u64 key = ~0ull;
            if (lane < rem) {
                int p = segBase[wave] + hs + lane;
                key = makeKey(cand_score[b * NCAND + p], (u32)p);
            }
            poolKey[tid] = key;
        }
        __syncthreads();

        // 2) rank-by-counting over the 320-pool + count valid
        u64 mine = poolKey[tid];
        int r = 0, V = 0;
        for (int f = 0; f < 320; f++) {
            u64 kf = poolKey[f];
            r += (kf < mine);
            V += (kf < KTHR);
        }
        int take = V < 64 ? V : 64;
        if (tid == 0) s_take = take;
        if (mine < KTHR && r < take) {
            winP[r] = (int)(mine & 0xFFFFFFFFu);
            atomicAdd(&cons[wave], 1);            // this segment consumed one
        }
        __syncthreads();
        if (take == 0) break;
        if (tid < 5) { h[tid] += cons[tid]; cons[tid] = 0; }

        // 3) gather window boxes (class-offset)
        if (tid < take) {
            int p = winP[tid];
            float4 v = ((const float4*)cand_box)[b * NCAND + p];
            float off = (float)cand_label[b * NCAND + p] * (IMGSZ + 1.0f);
            v.x = __fadd_rn(v.x, off); v.y = __fadd_rn(v.y, off);
            v.z = __fadd_rn(v.z, off); v.w = __fadd_rn(v.w, off);
            wb[tid] = v;
        }
        if (tid < 2) s_rej32[tid] = 0;
        __syncthreads();

        // 4) reject phase: window row (lane) vs accepted set (strided by wave)
        {
            bool rej = false;
            if (lane < take) {
                for (int s2 = wave; s2 < count; s2 += 5) {
                    if (suppress(accB[s2], wb[lane])) { rej = true; break; }
                }
            }
            u64 mask = __ballot(rej);
            if (lane == 0 && mask) {
                u32 lo = (u32)mask, hi = (u32)(mask >> 32);
                if (lo) atomicOr(&s_rej32[0], lo);
                if (hi) atomicOr(&s_rej32[1], hi);
            }
        }
        // 5) intra-window pair masks: wsup[rr] bit c == (rr suppresses c), c>rr
        for (int rr = wave; rr < take; rr += 5) {
            bool sp = false;
            if (lane < take && lane > rr) sp = suppress(wb[rr], wb[lane]);
            u64 mask = __ballot(sp);
            if (lane == 0) wsup[rr] = mask;
        }
        __syncthreads();

        // 6) greedy resolve within window (wave 0, registers only)
        if (wave == 0) {
            u64 supr = (lane < take) ? wsup[lane] : 0;
            u64 rejM = (u64)s_rej32[0] | ((u64)s_rej32[1] << 32);
            u64 aliveM = ((take >= 64) ? ~0ull : ((1ull << take) - 1ull)) & ~rejM;
            u64 accM = 0;
            for (int rr = 0; rr < take; rr++) {
                if ((aliveM >> rr) & 1) {
                    accM |= 1ull << rr;
                    u64 sr = __shfl(supr, rr);
                    aliveM &= ~sr;
                }
            }
            int na = __popcll(accM);
            int space = NDET - count;
            int takeA = na < space ? na : space;
            if (lane < take && ((accM >> lane) & 1)) {
                int pos = __popcll(accM & ((1ull << lane) - 1ull));
                if (pos < takeA) {
                    sel[count + pos] = winP[lane];
                    accB[count + pos] = wb[lane];
                }
            }
            if (lane == 0) s_count = count + takeA;
        }
        __syncthreads();
        count = s_count;
        if (count >= NDET) break;
    }
    __syncthreads();
    count = s_count;

    // emit top-100
    for (int s = tid; s < NDET; s += 320) {
        float4 bxv = make_float4(0.f, 0.f, 0.f, 0.f);
        float scv = 0.0f, lbv = -1.0f;
        if (s < count) {
            int p = sel[s];
            bxv = ((const float4*)cand_box)[b * NCAND + p];
            scv = cand_score[b * NCAND + p];
            lbv = (float)cand_label[b * NCAND + p];
        }
        ((float4*)out)[b * NDET + s] = bxv;                                  // boxes [0,3200)
        out[BATCH * NDET * 4 + b * NDET + s] = scv;                          // scores [3200,4000)
        out[BATCH * NDET * 4 + BATCH * NDET + b * NDET + s] = lbv;           // labels [4000,4800)
    }
}

extern "C" void kernel_launch(void* const* d_in, const int* in_sizes, int n_in,
                              void* d_out, int out_size, void* d_ws, size_t ws_size,
                              hipStream_t stream) {
    (void)in_sizes; (void)n_in; (void)out_size; (void)ws_size;
    const float* logits  = (const float*)d_in[0];
    const float* reg     = (const float*)d_in[1];
    const float* ctr     = (const float*)d_in[2];
    const float* anchors = (const float*)d_in[3];
    float* out = (float*)d_out;

    char* ws = (char*)d_ws;
    size_t off = 0;
    auto alloc = [&](size_t bytes) -> void* {
        off = (off + 255) & ~(size_t)255;
        void* p = ws + off;
        off += bytes;
        return p;
    };
    u32*   hist   = (u32*)  alloc((size_t)BATCH * 5 * NBUCK * 4);
    float* mscore = (float*)alloc((size_t)BATCH * TOTAL * 4);
    int*   mlabel = (int*)  alloc((size_t)BATCH * TOTAL * 4);
    float* cscore = (float*)alloc((size_t)BATCH * NCAND * 4);
    float* cbox   = (float*)alloc((size_t)BATCH * NCAND * 16);
    int*   clabel = (int*)  alloc((size_t)BATCH * NCAND * 4);

    hipMemsetAsync(hist, 0, (size_t)BATCH * 5 * NBUCK * 4, stream);
    score_kernel<<<dim3((TOTAL + 255) / 256, BATCH), 256, 0, stream>>>(logits, ctr, mscore, mlabel, hist);
    select_kernel<<<BATCH * 5, 512, 0, stream>>>(mscore, mlabel, anchors, reg, hist,
                                                 cscore, cbox, clabel);
    nms_kernel<<<BATCH, 320, 0, stream>>>(cscore, cbox, clabel, out);
}

// Round 9
// 157.782 us; speedup vs baseline: 4.3650x; 1.0967x over previous
//
#include <hip/hip_runtime.h>
#include <stdint.h>

typedef unsigned long long u64;
typedef unsigned int u32;

#define BATCH   8
#define TOTAL   21824
#define NCLS    80
#define NDET    100
#define IMGSZ   1024.0f
#define STHR    0.2f
#define NMST    0.6f
#define NBUCK   2048        /* monotone score buckets */
#define KGLOB   1000        /* global top-K prefix (== min per-level k) */

__device__ __forceinline__ float sigm(float x) { return 1.0f / (1.0f + expf(-x)); }

// Order-preserving map: ascending km == descending score.
__device__ __forceinline__ u32 mapKm(float s) {
    u32 u = __float_as_uint(s);
    u32 m = u ^ ((u & 0x80000000u) ? 0xFFFFFFFFu : 0x80000000u);
    return ~m;
}
// Composite key: ascending u64 == (score desc, anchor idx asc) — equals the
// reference's merged candidate order for any prefix <= 1000 (see theory).
__device__ __forceinline__ u64 makeKey(float s, u32 idx) {
    return (((u64)mapKm(s)) << 32) | (u64)idx;
}

// Monotone bucket: descending score -> ascending bucket. Valid scores (>0.2)
// land in [0,2016); masked -1.0 clamps to 2047.
__device__ __forceinline__ int bucketOf(float s) {
    int b = (int)(__fmul_rn(__fsub_rn(1.0f, s), 2520.0f));
    return b > (NBUCK - 1) ? (NBUCK - 1) : b;
}

// Bit-exact IoU suppression test (no FMA contraction).
__device__ __forceinline__ bool suppress(float4 a, float4 c) {
    float aa = __fmul_rn(fmaxf(__fsub_rn(a.z, a.x), 0.f), fmaxf(__fsub_rn(a.w, a.y), 0.f));
    float ac = __fmul_rn(fmaxf(__fsub_rn(c.z, c.x), 0.f), fmaxf(__fsub_rn(c.w, c.y), 0.f));
    float ltx = fmaxf(a.x, c.x), lty = fmaxf(a.y, c.y);
    float rbx = fminf(a.z, c.z), rby = fminf(a.w, c.w);
    float iw = fmaxf(__fsub_rn(rbx, ltx), 0.f), ih = fmaxf(__fsub_rn(rby, lty), 0.f);
    float inter = __fmul_rn(iw, ih);
    float uni = __fsub_rn(__fadd_rn(aa, ac), inter);
    float iou = __fdiv_rn(inter, fmaxf(uni, 1e-9f));
    return iou > NMST;
}

// ---------------- Kernel 1: coalesced score/argmax ----------------
__global__ __launch_bounds__(256) void score_kernel(
        const float* __restrict__ logits, const float* __restrict__ ctr,
        float* __restrict__ mscore, int* __restrict__ mlabel) {
    const int b = blockIdx.y;
    const int tid = threadIdx.x;
    const int wave = tid >> 6, lane = tid & 63;
    const int g = lane >> 2, j = lane & 3;
    const int rowBase = blockIdx.x * 256 + wave * 64;
#pragma unroll
    for (int t = 0; t < 4; t++) {
        int r = rowBase + 16 * t + g;
        bool valid = r < TOTAL;
        float best = -1e30f; int bi = 0;
        if (valid) {
            const float* rowp = logits + ((size_t)b * TOTAL + r) * NCLS + j * 4;
#pragma unroll
            for (int u = 0; u < 5; u++) {
                float4 v = *(const float4*)(rowp + u * 16);
                int c0 = u * 16 + j * 4;
                if (v.x > best) { best = v.x; bi = c0; }
                if (v.y > best) { best = v.y; bi = c0 + 1; }
                if (v.z > best) { best = v.z; bi = c0 + 2; }
                if (v.w > best) { best = v.w; bi = c0 + 3; }
            }
        }
        // merge 4 lanes of one row: max, tie -> lowest class index
#pragma unroll
        for (int off = 1; off <= 2; off <<= 1) {
            float ob = __shfl_xor(best, off);
            int obi = __shfl_xor(bi, off);
            if (ob > best || (ob == best && obi < bi)) { best = ob; bi = obi; }
        }
        if (valid && j == 0) {
            float c = ctr[(size_t)b * TOTAL + r];
            float sc = sqrtf(sigm(best) * sigm(c));
            float msc = (sc > STHR) ? sc : -1.0f;
            mscore[(size_t)b * TOTAL + r] = msc;
            mlabel[(size_t)b * TOTAL + r] = bi;
        }
    }
}

// ---------------- Kernel 2: histogram -> global top-K gather -> sort -> windowed NMS -> emit ----------------
__global__ __launch_bounds__(1024) void nms_kernel(
        const float* __restrict__ mscore, const int* __restrict__ mlabel,
        const float* __restrict__ anchors, const float* __restrict__ reg,
        float* __restrict__ out) {
    __shared__ u32 hist[NBUCK];
    __shared__ u64 keys[2048];
    __shared__ u64 skey[2048];
    __shared__ u32 waveSum[16], waveOff[16];
    __shared__ u32 sh_B;
    __shared__ int sh_cnt, s_count;
    __shared__ int accI[NDET];
    __shared__ float4 accB[NDET];   // class-offset boxes of accepted
    __shared__ float4 accR[NDET];   // raw (clamped) boxes of accepted
    __shared__ int wIdx[64];
    __shared__ float4 wb[64], wraw[64];
    __shared__ u64 wsup[64];
    __shared__ u32 s_rej32[2];

    const int b = blockIdx.x, tid = threadIdx.x;
    const int wave = tid >> 6, lane = tid & 63;
    const float* ms = mscore + (size_t)b * TOTAL;

    // Pass 0: zero histogram
    hist[tid] = 0; hist[tid + 1024] = 0;
    if (tid == 0) { sh_cnt = 0; s_count = 0; }
    __syncthreads();

    // Pass 1: per-batch score histogram (coalesced reads, LDS atomics)
    for (int i = tid; i < TOTAL; i += 1024)
        atomicAdd(&hist[bucketOf(ms[i])], 1u);
    __syncthreads();

    // Scan: thread t owns buckets 2t, 2t+1; find bucket of the KGLOB-th smallest.
    u32 h0 = hist[2 * tid], h1 = hist[2 * tid + 1];
    u32 s = h0 + h1;
    u32 incl = s;
    for (int o = 1; o < 64; o <<= 1) {
        u32 t2 = (u32)__shfl_up((int)incl, o);
        if (lane >= o) incl += t2;
    }
    if (lane == 63) waveSum[wave] = incl;
    __syncthreads();
    if (tid == 0) {
        u32 acc = 0;
#pragma unroll
        for (int w = 0; w < 16; w++) { waveOff[w] = acc; acc += waveSum[w]; }
    }
    __syncthreads();
    {
        u32 E = waveOff[wave] + incl - s;
        if (E < KGLOB && KGLOB <= E + h0) sh_B = (u32)(2 * tid);
        else if (E + h0 < KGLOB && KGLOB <= E + h0 + h1) sh_B = (u32)(2 * tid + 1);
    }
    __syncthreads();
    int Bstar = (int)sh_B;
    if (Bstar > 2015) Bstar = 2015;   // clamp to valid-score region (exact all-valid fallback)

    // Pass 2: gather downward-closed superset of global top-K (all bucket <= Bstar)
    for (int i = tid; i < TOTAL; i += 1024) {
        float sv = ms[i];
        if (bucketOf(sv) <= Bstar) {
            int pos = atomicAdd(&sh_cnt, 1);
            if (pos < 2048) keys[pos] = makeKey(sv, (u32)i);
        }
    }
    __syncthreads();
    int m = sh_cnt; if (m > 2048) m = 2048;

    // Sort by rank-by-counting (broadcast LDS reads; keys distinct)
    {
        u64 k0 = (tid < m) ? keys[tid] : ~0ull;
        u64 k1 = (tid + 1024 < m) ? keys[tid + 1024] : ~0ull;
        int r0 = 0, r1 = 0;
        for (int f = 0; f < m; f++) {
            u64 kf = keys[f];
            r0 += (kf < k0);
            r1 += (kf < k1);
        }
        if (tid < m) skey[r0] = k0;
        if (tid + 1024 < m) skey[r1] = k1;
    }
    __syncthreads();

    // Windowed greedy NMS over the sorted prefix
    int count = 0, E = 0;
    while (true) {
        int take = m - E; if (take > 64) take = 64;
        if (take <= 0) break;

        if (tid < take) {
            int idx = (int)(skey[E + tid] & 0xFFFFFFFFu);
            float4 a = ((const float4*)anchors)[idx];
            float4 r = ((const float4*)reg)[(size_t)b * TOTAL + idx];
            float cx = (a.x + a.z) * 0.5f;
            float cy = (a.y + a.w) * 0.5f;
            float x1 = fminf(fmaxf(cx - r.x, 0.0f), IMGSZ);
            float y1 = fminf(fmaxf(cy - r.y, 0.0f), IMGSZ);
            float x2 = fminf(fmaxf(cx + r.z, 0.0f), IMGSZ);
            float y2 = fminf(fmaxf(cy + r.w, 0.0f), IMGSZ);
            float4 raw = make_float4(x1, y1, x2, y2);
            float off = (float)mlabel[(size_t)b * TOTAL + idx] * (IMGSZ + 1.0f);
            float4 ob = make_float4(__fadd_rn(x1, off), __fadd_rn(y1, off),
                                    __fadd_rn(x2, off), __fadd_rn(y2, off));
            wraw[tid] = raw; wb[tid] = ob; wIdx[tid] = idx;
        }
        if (tid < 2) s_rej32[tid] = 0;
        __syncthreads();

        // reject phase: window element (lane) vs accepted set (strided by wave)
        {
            bool rej = false;
            if (lane < take) {
                for (int s2 = wave; s2 < count; s2 += 16) {
                    if (suppress(accB[s2], wb[lane])) { rej = true; break; }
                }
            }
            u64 mask = __ballot(rej);
            if (lane == 0 && mask) {
                u32 lo = (u32)mask, hi = (u32)(mask >> 32);
                if (lo) atomicOr(&s_rej32[0], lo);
                if (hi) atomicOr(&s_rej32[1], hi);
            }
        }
        // intra-window pair masks: wsup[rr] bit c == (rr suppresses c), c>rr
        for (int rr = wave; rr < take; rr += 16) {
            bool sp = false;
            if (lane < take && lane > rr) sp = suppress(wb[rr], wb[lane]);
            u64 mask = __ballot(sp);
            if (lane == 0) wsup[rr] = mask;
        }
        __syncthreads();

        // greedy resolve within window (wave 0, registers only)
        if (wave == 0) {
            u64 supr = (lane < take) ? wsup[lane] : 0;
            u64 rejM = (u64)s_rej32[0] | ((u64)s_rej32[1] << 32);
            u64 aliveM = ((take >= 64) ? ~0ull : ((1ull << take) - 1ull)) & ~rejM;
            u64 accM = 0;
            for (int rr = 0; rr < take; rr++) {
                if ((aliveM >> rr) & 1) {
                    accM |= 1ull << rr;
                    u64 sr = __shfl(supr, rr);
                    aliveM &= ~sr;
                }
            }
            int na = __popcll(accM);
            int space = NDET - count;
            int takeA = na < space ? na : space;
            if (lane < take && ((accM >> lane) & 1)) {
                int pos = __popcll(accM & ((1ull << lane) - 1ull));
                if (pos < takeA) {
                    accI[count + pos] = wIdx[lane];
                    accB[count + pos] = wb[lane];
                    accR[count + pos] = wraw[lane];
                }
            }
            if (lane == 0) s_count = count + takeA;
        }
        __syncthreads();
        count = s_count;
        E += take;
        if (count >= NDET) break;
    }
    __syncthreads();

    // emit top-100
    for (int s2 = tid; s2 < NDET; s2 += 1024) {
        float4 bxv = make_float4(0.f, 0.f, 0.f, 0.f);
        float scv = 0.0f, lbv = -1.0f;
        if (s2 < count) {
            int idx = accI[s2];
            bxv = accR[s2];
            scv = ms[idx];
            lbv = (float)mlabel[(size_t)b * TOTAL + idx];
        }
        ((float4*)out)[b * NDET + s2] = bxv;                                  // boxes [0,3200)
        out[BATCH * NDET * 4 + b * NDET + s2] = scv;                          // scores [3200,4000)
        out[BATCH * NDET * 4 + BATCH * NDET + b * NDET + s2] = lbv;           // labels [4000,4800)
    }
}

extern "C" void kernel_launch(void* const* d_in, const int* in_sizes, int n_in,
                              void* d_out, int out_size, void* d_ws, size_t ws_size,
                              hipStream_t stream) {
    (void)in_sizes; (void)n_in; (void)out_size; (void)ws_size;
    const float* logits  = (const float*)d_in[0];
    const float* reg     = (const float*)d_in[1];
    const float* ctr     = (const float*)d_in[2];
    const float* anchors = (const float*)d_in[3];
    float* out = (float*)d_out;

    char* ws = (char*)d_ws;
    size_t off = 0;
    auto alloc = [&](size_t bytes) -> void* {
        off = (off + 255) & ~(size_t)255;
        void* p = ws + off;
        off += bytes;
        return p;
    };
    float* mscore = (float*)alloc((size_t)BATCH * TOTAL * 4);
    int*   mlabel = (int*)  alloc((size_t)BATCH * TOTAL * 4);

    score_kernel<<<dim3((TOTAL + 255) / 256, BATCH), 256, 0, stream>>>(logits, ctr, mscore, mlabel);
    nms_kernel<<<BATCH, 1024, 0, stream>>>(mscore, mlabel, anchors, reg, out);
}